// Round 4
// baseline (1351.719 us; speedup 1.0000x reference)
//
#include <hip/hip_runtime.h>
#include <hip/hip_bf16.h>

#define SQ   4096
#define HIDN 2048
#define NH   16
#define NKV  8
#define HD   128
#define QD   2048   // NH*HD
#define KD   1024   // NKV*HD
#define KVB  64

typedef __bf16 bf16x8 __attribute__((ext_vector_type(8)));
typedef float  f32x4  __attribute__((ext_vector_type(4)));

__device__ __forceinline__ float b2f(unsigned short u) {
    union { float f; unsigned int i; } v; v.i = ((unsigned int)u) << 16; return v.f;
}
__device__ __forceinline__ unsigned short f2b(float f) {
    union { float f; unsigned int i; } v; v.f = f;
    unsigned int i = v.i;
    return (unsigned short)((i + 0x7FFFu + ((i >> 16) & 1u)) >> 16);
}

__device__ __forceinline__ void gload_lds16(const void* g, void* l) {
    __builtin_amdgcn_global_load_lds(
        (const __attribute__((address_space(1))) unsigned int*)g,
        (__attribute__((address_space(3))) unsigned int*)l, 16, 0, 0);
}

#define MFMA16(a, b, c) __builtin_amdgcn_mfma_f32_16x16x32_bf16(a, b, c, 0, 0, 0)

// DPP row-rotate (within 16-lane rows) for cross-lane reduce on the VALU pipe.
#define DPP_ROR(x, n) __int_as_float(__builtin_amdgcn_update_dpp(            \
    __float_as_int(x), __float_as_int(x), 0x120 + (n), 0xF, 0xF, false))

__device__ __forceinline__ float rowmax16(float x) {
    x = fmaxf(x, DPP_ROR(x, 1));
    x = fmaxf(x, DPP_ROR(x, 2));
    x = fmaxf(x, DPP_ROR(x, 4));
    x = fmaxf(x, DPP_ROR(x, 8));
    return x;
}
__device__ __forceinline__ float rowsum16(float x) {
    x += DPP_ROR(x, 1);
    x += DPP_ROR(x, 2);
    x += DPP_ROR(x, 4);
    x += DPP_ROR(x, 8);
    return x;
}

// ---------------------------------------------------------------------------
// merged f32 -> bf16 convert for all 5 tensors (one launch)
// ---------------------------------------------------------------------------
__global__ __launch_bounds__(256) void cvt_all(const float* __restrict__ h,
                                               const float* __restrict__ wq,
                                               const float* __restrict__ wk,
                                               const float* __restrict__ wv,
                                               const float* __restrict__ wo,
                                               unsigned short* __restrict__ oh,
                                               unsigned short* __restrict__ owq,
                                               unsigned short* __restrict__ owk,
                                               unsigned short* __restrict__ owv,
                                               unsigned short* __restrict__ owo) {
    int i = blockIdx.x * 256 + threadIdx.x;  // float4 index, 5M total
    const float* src; unsigned short* dst; int off;
    if (i < 2097152)      { src = h;  dst = oh;  off = i; }
    else if (i < 3145728) { src = wq; dst = owq; off = i - 2097152; }
    else if (i < 3670016) { src = wk; dst = owk; off = i - 3145728; }
    else if (i < 4194304) { src = wv; dst = owv; off = i - 3670016; }
    else                  { src = wo; dst = owo; off = i - 4194304; }
    float4 v = ((const float4*)src)[off];
    ushort4 u;
    u.x = f2b(v.x); u.y = f2b(v.y); u.z = f2b(v.z); u.w = f2b(v.w);
    ((ushort4*)dst)[off] = u;
}

// ---------------------------------------------------------------------------
// RoPE cos/sin table: [S][64] each (float: invf rel-err ~1e-7, fine for bf16)
// ---------------------------------------------------------------------------
__global__ __launch_bounds__(256) void rope_table(const int* __restrict__ pos,
                                                  float* __restrict__ cosT,
                                                  float* __restrict__ sinT) {
    int i = blockIdx.x * 256 + threadIdx.x;  // S*64 total
    int s = i >> 6, j = i & 63;
    float invf = __expf(-(float)j * (1.3815510557964274f / 6.4f));  // ln(1e6)/64
    float a = (float)pos[s] * invf;
    cosT[i] = cosf(a);
    sinT[i] = sinf(a);
}

// ---------------------------------------------------------------------------
// GEMM: C[M][N] = A[M][K] @ B[N][K]^T + bias   (A,B bf16; 128x128 tile)
// EPI 0: bf16 row-major   EPI 1: f32 row-major   EPI 2: bf16 transposed C[N][M]
// XCD-bijective block swizzle (nwg % 8 == 0 for all our grids).
// ---------------------------------------------------------------------------
template <int EPI>
__global__ __launch_bounds__(256) void gemm128(const unsigned short* __restrict__ A,
                                               const unsigned short* __restrict__ B,
                                               const float* __restrict__ bias,
                                               void* __restrict__ Cout,
                                               int M, int N, int K) {
    __shared__ unsigned short As[128 * 32];
    __shared__ unsigned short Bs[128 * 32];
    const int tid = threadIdx.x, wid = tid >> 6, lane = tid & 63;
    const int g = lane >> 4, c = lane & 15;
    const int wr = wid >> 1, wc = wid & 1;
    const int orig = blockIdx.y * gridDim.x + blockIdx.x;
    const int cpx = (gridDim.x * gridDim.y) >> 3;
    const int wg = (orig & 7) * cpx + (orig >> 3);
    const int bx = wg % gridDim.x, by = wg / gridDim.x;
    const long rowbase = (long)by * 128;
    const long colbase = (long)bx * 128;

    f32x4 acc[4][4];
#pragma unroll
    for (int m = 0; m < 4; ++m)
#pragma unroll
        for (int n = 0; n < 4; ++n) acc[m][n] = (f32x4){0.f, 0.f, 0.f, 0.f};

    const int ch0 = (wid * 2) * 64 + lane;
    const int ch1 = (wid * 2 + 1) * 64 + lane;

    for (int kt = 0; kt < K; kt += 32) {
        gload_lds16(A + ((rowbase + (ch0 >> 2)) * K + kt + (ch0 & 3) * 8),
                    As + (wid * 2) * 64 * 8);
        gload_lds16(B + ((colbase + (ch0 >> 2)) * K + kt + (ch0 & 3) * 8),
                    Bs + (wid * 2) * 64 * 8);
        gload_lds16(A + ((rowbase + (ch1 >> 2)) * K + kt + (ch1 & 3) * 8),
                    As + (wid * 2 + 1) * 64 * 8);
        gload_lds16(B + ((colbase + (ch1 >> 2)) * K + kt + (ch1 & 3) * 8),
                    Bs + (wid * 2 + 1) * 64 * 8);
        __syncthreads();
        bf16x8 a[4], b[4];
#pragma unroll
        for (int m = 0; m < 4; ++m)
            a[m] = *(const bf16x8*)(As + (wr * 64 + m * 16 + c) * 32 + g * 8);
#pragma unroll
        for (int n = 0; n < 4; ++n)
            b[n] = *(const bf16x8*)(Bs + (wc * 64 + n * 16 + c) * 32 + g * 8);
#pragma unroll
        for (int m = 0; m < 4; ++m)
#pragma unroll
            for (int n = 0; n < 4; ++n) acc[m][n] = MFMA16(a[m], b[n], acc[m][n]);
        __syncthreads();
    }

#pragma unroll
    for (int m = 0; m < 4; ++m) {
        const long grow0 = rowbase + wr * 64 + m * 16 + g * 4;
#pragma unroll
        for (int n = 0; n < 4; ++n) {
            const long gcol = colbase + wc * 64 + n * 16 + c;
            const float bs = bias[gcol];
            if (EPI == 0) {
                unsigned short* C = (unsigned short*)Cout;
#pragma unroll
                for (int r = 0; r < 4; ++r)
                    C[(grow0 + r) * N + gcol] = f2b(acc[m][n][r] + bs);
            } else if (EPI == 1) {
                float* C = (float*)Cout;
#pragma unroll
                for (int r = 0; r < 4; ++r)
                    C[(grow0 + r) * N + gcol] = acc[m][n][r] + bs;
            } else {
                unsigned short* C = (unsigned short*)Cout;
                ushort4 pk;
                pk.x = f2b(acc[m][n][0] + bs);
                pk.y = f2b(acc[m][n][1] + bs);
                pk.z = f2b(acc[m][n][2] + bs);
                pk.w = f2b(acc[m][n][3] + bs);
                *(ushort4*)(C + gcol * (long)M + grow0) = pk;
            }
        }
    }
}

// ---------------------------------------------------------------------------
// RMSNorm + RoPE + transpose to head-major [nh][S][HD]; one wave per (s,h)
// ---------------------------------------------------------------------------
__global__ __launch_bounds__(256) void norm_rope(const unsigned short* __restrict__ proj,
                                                 int nh,
                                                 const float* __restrict__ w,
                                                 const float* __restrict__ cosT,
                                                 const float* __restrict__ sinT,
                                                 unsigned short* __restrict__ outt,
                                                 float oscale) {
    int wv = (blockIdx.x * 256 + threadIdx.x) >> 6;  // over S*nh
    int lane = threadIdx.x & 63;
    int s = wv / nh, h = wv - s * nh;
    const unsigned short* p = proj + (size_t)s * (nh * HD) + h * HD;
    float x1 = b2f(p[lane]);
    float x2 = b2f(p[lane + 64]);
    float ss = x1 * x1 + x2 * x2;
#pragma unroll
    for (int d = 1; d < 64; d <<= 1) ss += __shfl_xor(ss, d);
    float r = rsqrtf(ss * (1.f / 128.f) + 1e-6f);
    x1 *= r * w[lane];
    x2 *= r * w[lane + 64];
    float cs = cosT[s * 64 + lane], sn = sinT[s * 64 + lane];
    unsigned short o1 = f2b((x1 * cs - x2 * sn) * oscale);
    unsigned short o2 = f2b((x2 * cs + x1 * sn) * oscale);
    unsigned short* q = outt + ((size_t)h * SQ + s) * HD;
    q[lane] = o1;
    q[lane + 64] = o2;
}

// ---------------------------------------------------------------------------
// Causal flash attention v4: 8 waves/block, 1 block/CU, dual q-chunk per wave.
// qt: [NH][S][HD] pre-scaled by scale*log2e; kt: [NKV][S][HD]; vt: [NKV][HD][S]
// aout: [S][QD] bf16.
// Grid 256: h = id&15, qc = id>>4 (0..15). Wave w handles 16 q-rows of chunk
// qc (m=0) AND 16 q-rows of chunk 31-qc (m=1): total MFMA work per block is
// uniform (66 m-tiles) -- perfect static balance, no scheduler assumptions.
// kv tile 64, K/V double-buffered LDS (XOR-swizzled both sides), per-wave P
// in LDS. LDS 96KB -> 1 block/CU, 8 waves = 2 waves/SIMD.
// ---------------------------------------------------------------------------
__global__ __launch_bounds__(512, 2) void fattn(const unsigned short* __restrict__ qt,
                                                const unsigned short* __restrict__ kt,
                                                const unsigned short* __restrict__ vt,
                                                unsigned short* __restrict__ aout) {
    __shared__ unsigned short Ks[2][KVB * HD];   // [64 kv][128 d], key=((row>>2)&7)<<4
    __shared__ unsigned short Vs[2][HD * KVB];   // [128 d][64 kv], key=(row&7)<<4
    __shared__ unsigned short Pl[8][32][64];     // per-wave P, key=(row&7)<<4
    const int tid = threadIdx.x, wid = tid >> 6, lane = tid & 63;
    const int g = lane >> 4, c = lane & 15;
    const int id = blockIdx.x;
    const int h = id & 15, qc = id >> 4, hk = h >> 1;
    const int row0A = qc * 128 + wid * 16;          // m=0 chunk (near)
    const int row0B = (31 - qc) * 128 + wid * 16;   // m=1 chunk (far)
    const unsigned short* qh = qt + (size_t)h * SQ * HD;
    const unsigned short* kh = kt + (size_t)hk * SQ * HD;
    const unsigned short* vh = vt + (size_t)hk * HD * SQ;
    const int ntile = 2 * (31 - qc) + 2;
    char* plw = (char*)&Pl[wid][0][0];

    // Q fragments: m=0 near chunk, m=1 far chunk
    bf16x8 qa[2][4];
#pragma unroll
    for (int ks = 0; ks < 4; ++ks) {
        qa[0][ks] = *(const bf16x8*)(qh + (size_t)(row0A + c) * HD + ks * 32 + g * 8);
        qa[1][ks] = *(const bf16x8*)(qh + (size_t)(row0B + c) * HD + ks * 32 + g * 8);
    }

    f32x4 o[2][8];
#pragma unroll
    for (int m = 0; m < 2; ++m)
#pragma unroll
        for (int df = 0; df < 8; ++df) o[m][df] = (f32x4){0.f, 0.f, 0.f, 0.f};
    float mrow[2][4], lrow[2][4];
#pragma unroll
    for (int m = 0; m < 2; ++m)
#pragma unroll
        for (int r = 0; r < 4; ++r) { mrow[m][r] = -1e30f; lrow[m][r] = 0.f; }

    // staging: 16 x 1KB granules per tensor, each of 8 waves takes 2 of each
    auto stage = [&](int b, int t) {
        const int kv0 = t * KVB;
#pragma unroll
        for (int i = 0; i < 2; ++i) {
            const int gi = wid * 2 + i;
            const int P = gi * 1024 + lane * 16;
            const int rk = P >> 8;                                  // K row
            const int Uk = (P & 255) ^ (((rk >> 2) & 7) << 4);
            gload_lds16(kh + (size_t)(kv0 + rk) * HD + (Uk >> 1),
                        (char*)Ks[b] + gi * 1024);
            const int rv = P >> 7;                                  // V row (d)
            const int Uv = (P & 127) ^ ((rv & 7) << 4);
            gload_lds16(vh + (size_t)rv * SQ + kv0 + (Uv >> 1),
                        (char*)Vs[b] + gi * 1024);
        }
    };

    stage(0, 0);
    asm volatile("s_waitcnt vmcnt(0)" ::: "memory");
    __syncthreads();

#define QK_BODY(DO0)                                                          \
    _Pragma("unroll") for (int nf = 0; nf < 4; ++nf) {                        \
        const int krow = (c << 2) + nf;                                       \
        const int key = (c & 7) << 4;                                         \
        _Pragma("unroll") for (int ks = 0; ks < 4; ++ks) {                    \
            bf16x8 kf = *(const bf16x8*)((const char*)Ks[bcur] + krow * 256 + \
                                         ((ks * 64 + g * 16) ^ key));         \
            if (DO0) sa[0][nf] = MFMA16(qa[0][ks], kf, sa[0][nf]);            \
            sa[1][nf] = MFMA16(qa[1][ks], kf, sa[1][nf]);                     \
        }                                                                     \
    }

#define PV_BODY(DO0)                                                          \
    _Pragma("unroll") for (int ks = 0; ks < 2; ++ks) {                        \
        const int pk_ = (ks * 64 + g * 16) ^ ((c & 7) << 4);                  \
        bf16x8 pa1 = *(const bf16x8*)(plw + (16 + c) * 128 + pk_);            \
        bf16x8 pa0{};                                                         \
        if (DO0) pa0 = *(const bf16x8*)(plw + c * 128 + pk_);                 \
        _Pragma("unroll") for (int df = 0; df < 8; ++df) {                    \
            const int rd = df * 16 + c;                                       \
            bf16x8 vb = *(const bf16x8*)((const char*)Vs[bcur] + rd * 128 +   \
                                         ((ks * 64 + g * 16) ^ ((rd & 7) << 4))); \
            if (DO0) o[0][df] = MFMA16(pa0, vb, o[0][df]);                    \
            o[1][df] = MFMA16(pa1, vb, o[1][df]);                             \
        }                                                                     \
    }

    int bcur = 0;
    for (int j = 0; j < ntile; ++j) {
        const int kv0 = j * KVB;
        if (j + 1 < ntile) stage(bcur ^ 1, j + 1);

        const bool act0 = (kv0 <= row0A + 15);
        const bool act1 = (kv0 <= row0B + 15);
        if (act1) {
            const int mlo = act0 ? 0 : 1;
            f32x4 sa[2][4];
#pragma unroll
            for (int m = 0; m < 2; ++m)
#pragma unroll
                for (int nf = 0; nf < 4; ++nf) sa[m][nf] = (f32x4){0.f, 0.f, 0.f, 0.f};
            __builtin_amdgcn_s_setprio(1);
            if (act0) { QK_BODY(1) } else { QK_BODY(0) }
            __builtin_amdgcn_s_setprio(0);
            // ---- causal mask (col = kv0 + 4c + nf; only near the diagonal)
            const int rb[2] = {row0A, row0B};
            for (int m = mlo; m < 2; ++m) {
                if (kv0 + 63 > rb[m]) {
#pragma unroll
                    for (int nf = 0; nf < 4; ++nf) {
                        const int col = kv0 + (c << 2) + nf;
#pragma unroll
                        for (int r = 0; r < 4; ++r) {
                            int row = rb[m] + g * 4 + r;
                            if (col > row) sa[m][nf][r] = -1e30f;
                        }
                    }
                }
            }
            // ---- online softmax in exp2 domain, defer-max (T13)
            float nmax[2][4];
            int small = 1;
            for (int m = mlo; m < 2; ++m)
#pragma unroll
                for (int r = 0; r < 4; ++r) {
                    float mx = fmaxf(fmaxf(sa[m][0][r], sa[m][1][r]),
                                     fmaxf(sa[m][2][r], sa[m][3][r]));
                    mx = rowmax16(mx);
                    nmax[m][r] = mx;
                    small &= (mx <= mrow[m][r] + 8.0f);
                }
            if (!__all(small)) {
                for (int m = mlo; m < 2; ++m) {
                    float psc[4];
#pragma unroll
                    for (int r = 0; r < 4; ++r) {
                        float mn = fmaxf(mrow[m][r], nmax[m][r]);
                        psc[r] = __builtin_amdgcn_exp2f(mrow[m][r] - mn);
                        mrow[m][r] = mn;
                        lrow[m][r] *= psc[r];
                    }
#pragma unroll
                    for (int df = 0; df < 8; ++df)
#pragma unroll
                        for (int r = 0; r < 4; ++r) o[m][df][r] *= psc[r];
                }
            }
            for (int m = mlo; m < 2; ++m)
#pragma unroll
                for (int r = 0; r < 4; ++r) {
                    float rs = 0.f;
#pragma unroll
                    for (int nf = 0; nf < 4; ++nf) {
                        float p = __builtin_amdgcn_exp2f(sa[m][nf][r] - mrow[m][r]);
                        sa[m][nf][r] = p;
                        rs += p;
                    }
                    lrow[m][r] += rowsum16(rs);
                }
            // ---- P -> LDS: 4 consecutive kv per lane -> 2x cvt_pk + b64 write
            for (int m = mlo; m < 2; ++m)
#pragma unroll
                for (int r = 0; r < 4; ++r) {
                    unsigned int lo, hi;
                    asm("v_cvt_pk_bf16_f32 %0, %1, %2"
                        : "=v"(lo) : "v"(sa[m][0][r]), "v"(sa[m][1][r]));
                    asm("v_cvt_pk_bf16_f32 %0, %1, %2"
                        : "=v"(hi) : "v"(sa[m][2][r]), "v"(sa[m][3][r]));
                    const int row = m * 16 + g * 4 + r;
                    const int pcol = (c * 8) ^ ((row & 7) << 4);
                    *(uint2*)(plw + row * 128 + pcol) = make_uint2(lo, hi);
                }
            // ---- PV
            __builtin_amdgcn_s_setprio(1);
            if (act0) { PV_BODY(1) } else { PV_BODY(0) }
            __builtin_amdgcn_s_setprio(0);
        }
        asm volatile("s_waitcnt vmcnt(0)" ::: "memory");
        __syncthreads();
        bcur ^= 1;
    }

    const int rb[2] = {row0A, row0B};
#pragma unroll
    for (int m = 0; m < 2; ++m) {
        float inv[4];
#pragma unroll
        for (int r = 0; r < 4; ++r) inv[r] = 1.f / lrow[m][r];
#pragma unroll
        for (int df = 0; df < 8; ++df)
#pragma unroll
            for (int r = 0; r < 4; ++r) {
                size_t row = rb[m] + g * 4 + r;
                aout[row * QD + h * HD + df * 16 + c] = f2b(o[m][df][r] * inv[r]);
            }
    }
#undef QK_BODY
#undef PV_BODY
}

// ---------------------------------------------------------------------------
extern "C" void kernel_launch(void* const* d_in, const int* in_sizes, int n_in,
                              void* d_out, int out_size, void* d_ws, size_t ws_size,
                              hipStream_t stream) {
    const int*   positions = (const int*)d_in[0];
    const float* hidden    = (const float*)d_in[1];
    const float* wq        = (const float*)d_in[2];
    const float* bq        = (const float*)d_in[3];
    const float* wk        = (const float*)d_in[4];
    const float* bk        = (const float*)d_in[5];
    const float* wv        = (const float*)d_in[6];
    const float* bv        = (const float*)d_in[7];
    const float* wo        = (const float*)d_in[8];
    const float* bo        = (const float*)d_in[9];
    const float* qnw       = (const float*)d_in[10];
    const float* knw       = (const float*)d_in[11];
    float* out = (float*)d_out;

    char* w = (char*)d_ws;
    unsigned short* hidden_b = (unsigned short*)(w);                 // 16 MB
    unsigned short* wq_b     = (unsigned short*)(w + 16777216);      //  8 MB
    unsigned short* wk_b     = (unsigned short*)(w + 25165824);      //  4 MB
    unsigned short* wv_b     = (unsigned short*)(w + 29360128);      //  4 MB
    unsigned short* wo_b     = (unsigned short*)(w + 33554432);      //  8 MB
    unsigned short* qproj    = (unsigned short*)(w + 41943040);      // 16 MB (aliased as attn out)
    unsigned short* kproj    = (unsigned short*)(w + 58720256);      //  8 MB
    unsigned short* q_t      = (unsigned short*)(w + 67108864);      // 16 MB
    unsigned short* k_t      = (unsigned short*)(w + 83886080);      //  8 MB
    unsigned short* v_t      = (unsigned short*)(w + 92274688);      //  8 MB
    float*          cosT     = (float*)(w + 100663296);              //  1 MB
    float*          sinT     = (float*)(w + 101711872);              //  1 MB
    unsigned short* attn     = qproj;  // reuse (qproj consumed before fattn)

    // 1. converts (one launch)
    cvt_all<<<20480, 256, 0, stream>>>(hidden, wq, wk, wv, wo,
                                       hidden_b, wq_b, wk_b, wv_b, wo_b);
    // 2. rope table
    rope_table<<<SQ * 64 / 256, 256, 0, stream>>>(positions, cosT, sinT);
    // 3. projections
    gemm128<0><<<dim3(QD / 128, SQ / 128), 256, 0, stream>>>(hidden_b, wq_b, bq, qproj, SQ, QD, HIDN);
    gemm128<0><<<dim3(KD / 128, SQ / 128), 256, 0, stream>>>(hidden_b, wk_b, bk, kproj, SQ, KD, HIDN);
    gemm128<2><<<dim3(KD / 128, SQ / 128), 256, 0, stream>>>(hidden_b, wv_b, bv, v_t, SQ, KD, HIDN);
    // 4. norm + rope (q pre-scaled by 1/sqrt(D) * log2(e) for exp2-domain softmax)
    norm_rope<<<SQ * NH / 4, 256, 0, stream>>>(qproj, NH, qnw, cosT, sinT, q_t,
                                               (float)(0.08838834764831845 * 1.4426950408889634));
    norm_rope<<<SQ * NKV / 4, 256, 0, stream>>>(kproj, NKV, knw, cosT, sinT, k_t, 1.0f);
    // 5. attention
    fattn<<<256, 512, 0, stream>>>(q_t, k_t, v_t, attn);
    // 6. output projection (f32 out)
    gemm128<1><<<dim3(QD / 128, SQ / 128), 256, 0, stream>>>(attn, wo_b, bo, out, SQ, QD, HIDN);
}

// Round 5
// 505.703 us; speedup vs baseline: 2.6729x; 2.6729x over previous
//
#include <hip/hip_runtime.h>
#include <hip/hip_bf16.h>

#define SQ   4096
#define HIDN 2048
#define NH   16
#define NKV  8
#define HD   128
#define QD   2048   // NH*HD
#define KD   1024   // NKV*HD
#define KVB  64

typedef __bf16 bf16x8 __attribute__((ext_vector_type(8)));
typedef float  f32x4  __attribute__((ext_vector_type(4)));

__device__ __forceinline__ float b2f(unsigned short u) {
    union { float f; unsigned int i; } v; v.i = ((unsigned int)u) << 16; return v.f;
}
__device__ __forceinline__ unsigned short f2b(float f) {
    union { float f; unsigned int i; } v; v.f = f;
    unsigned int i = v.i;
    return (unsigned short)((i + 0x7FFFu + ((i >> 16) & 1u)) >> 16);
}

__device__ __forceinline__ void gload_lds16(const void* g, void* l) {
    __builtin_amdgcn_global_load_lds(
        (const __attribute__((address_space(1))) unsigned int*)g,
        (__attribute__((address_space(3))) unsigned int*)l, 16, 0, 0);
}

#define MFMA16(a, b, c) __builtin_amdgcn_mfma_f32_16x16x32_bf16(a, b, c, 0, 0, 0)

// DPP row-rotate (within 16-lane rows) for cross-lane reduce on the VALU pipe.
#define DPP_ROR(x, n) __int_as_float(__builtin_amdgcn_update_dpp(            \
    __float_as_int(x), __float_as_int(x), 0x120 + (n), 0xF, 0xF, false))

__device__ __forceinline__ float rowmax16(float x) {
    x = fmaxf(x, DPP_ROR(x, 1));
    x = fmaxf(x, DPP_ROR(x, 2));
    x = fmaxf(x, DPP_ROR(x, 4));
    x = fmaxf(x, DPP_ROR(x, 8));
    return x;
}
__device__ __forceinline__ float rowsum16(float x) {
    x += DPP_ROR(x, 1);
    x += DPP_ROR(x, 2);
    x += DPP_ROR(x, 4);
    x += DPP_ROR(x, 8);
    return x;
}

// ---------------------------------------------------------------------------
// merged f32 -> bf16 convert for all 5 tensors (one launch)
// ---------------------------------------------------------------------------
__global__ __launch_bounds__(256) void cvt_all(const float* __restrict__ h,
                                               const float* __restrict__ wq,
                                               const float* __restrict__ wk,
                                               const float* __restrict__ wv,
                                               const float* __restrict__ wo,
                                               unsigned short* __restrict__ oh,
                                               unsigned short* __restrict__ owq,
                                               unsigned short* __restrict__ owk,
                                               unsigned short* __restrict__ owv,
                                               unsigned short* __restrict__ owo) {
    int i = blockIdx.x * 256 + threadIdx.x;  // float4 index, 5M total
    const float* src; unsigned short* dst; int off;
    if (i < 2097152)      { src = h;  dst = oh;  off = i; }
    else if (i < 3145728) { src = wq; dst = owq; off = i - 2097152; }
    else if (i < 3670016) { src = wk; dst = owk; off = i - 3145728; }
    else if (i < 4194304) { src = wv; dst = owv; off = i - 3670016; }
    else                  { src = wo; dst = owo; off = i - 4194304; }
    float4 v = ((const float4*)src)[off];
    ushort4 u;
    u.x = f2b(v.x); u.y = f2b(v.y); u.z = f2b(v.z); u.w = f2b(v.w);
    ((ushort4*)dst)[off] = u;
}

// ---------------------------------------------------------------------------
// RoPE cos/sin table: [S][64] each
// ---------------------------------------------------------------------------
__global__ __launch_bounds__(256) void rope_table(const int* __restrict__ pos,
                                                  float* __restrict__ cosT,
                                                  float* __restrict__ sinT) {
    int i = blockIdx.x * 256 + threadIdx.x;  // S*64 total
    int s = i >> 6, j = i & 63;
    float invf = __expf(-(float)j * (1.3815510557964274f / 6.4f));  // ln(1e6)/64
    float a = (float)pos[s] * invf;
    cosT[i] = cosf(a);
    sinT[i] = sinf(a);
}

// ---------------------------------------------------------------------------
// GEMM: C[M][N] = A[M][K] @ B[N][K]^T + bias   (A,B bf16; 128x128 tile)
// EPI 0: bf16 row-major   EPI 1: f32 row-major   EPI 2: bf16 transposed C[N][M]
// XCD-bijective block swizzle (nwg % 8 == 0 for all our grids).
// ---------------------------------------------------------------------------
template <int EPI>
__global__ __launch_bounds__(256) void gemm128(const unsigned short* __restrict__ A,
                                               const unsigned short* __restrict__ B,
                                               const float* __restrict__ bias,
                                               void* __restrict__ Cout,
                                               int M, int N, int K) {
    __shared__ unsigned short As[128 * 32];
    __shared__ unsigned short Bs[128 * 32];
    const int tid = threadIdx.x, wid = tid >> 6, lane = tid & 63;
    const int g = lane >> 4, c = lane & 15;
    const int wr = wid >> 1, wc = wid & 1;
    const int orig = blockIdx.y * gridDim.x + blockIdx.x;
    const int cpx = (gridDim.x * gridDim.y) >> 3;
    const int wg = (orig & 7) * cpx + (orig >> 3);
    const int bx = wg % gridDim.x, by = wg / gridDim.x;
    const long rowbase = (long)by * 128;
    const long colbase = (long)bx * 128;

    f32x4 acc[4][4];
#pragma unroll
    for (int m = 0; m < 4; ++m)
#pragma unroll
        for (int n = 0; n < 4; ++n) acc[m][n] = (f32x4){0.f, 0.f, 0.f, 0.f};

    const int ch0 = (wid * 2) * 64 + lane;
    const int ch1 = (wid * 2 + 1) * 64 + lane;

    for (int kt = 0; kt < K; kt += 32) {
        gload_lds16(A + ((rowbase + (ch0 >> 2)) * K + kt + (ch0 & 3) * 8),
                    As + (wid * 2) * 64 * 8);
        gload_lds16(B + ((colbase + (ch0 >> 2)) * K + kt + (ch0 & 3) * 8),
                    Bs + (wid * 2) * 64 * 8);
        gload_lds16(A + ((rowbase + (ch1 >> 2)) * K + kt + (ch1 & 3) * 8),
                    As + (wid * 2 + 1) * 64 * 8);
        gload_lds16(B + ((colbase + (ch1 >> 2)) * K + kt + (ch1 & 3) * 8),
                    Bs + (wid * 2 + 1) * 64 * 8);
        __syncthreads();
        bf16x8 a[4], b[4];
#pragma unroll
        for (int m = 0; m < 4; ++m)
            a[m] = *(const bf16x8*)(As + (wr * 64 + m * 16 + c) * 32 + g * 8);
#pragma unroll
        for (int n = 0; n < 4; ++n)
            b[n] = *(const bf16x8*)(Bs + (wc * 64 + n * 16 + c) * 32 + g * 8);
#pragma unroll
        for (int m = 0; m < 4; ++m)
#pragma unroll
            for (int n = 0; n < 4; ++n) acc[m][n] = MFMA16(a[m], b[n], acc[m][n]);
        __syncthreads();
    }

#pragma unroll
    for (int m = 0; m < 4; ++m) {
        const long grow0 = rowbase + wr * 64 + m * 16 + g * 4;
#pragma unroll
        for (int n = 0; n < 4; ++n) {
            const long gcol = colbase + wc * 64 + n * 16 + c;
            const float bs = bias[gcol];
            if (EPI == 0) {
                unsigned short* C = (unsigned short*)Cout;
#pragma unroll
                for (int r = 0; r < 4; ++r)
                    C[(grow0 + r) * N + gcol] = f2b(acc[m][n][r] + bs);
            } else if (EPI == 1) {
                float* C = (float*)Cout;
#pragma unroll
                for (int r = 0; r < 4; ++r)
                    C[(grow0 + r) * N + gcol] = acc[m][n][r] + bs;
            } else {
                unsigned short* C = (unsigned short*)Cout;
                ushort4 pk;
                pk.x = f2b(acc[m][n][0] + bs);
                pk.y = f2b(acc[m][n][1] + bs);
                pk.z = f2b(acc[m][n][2] + bs);
                pk.w = f2b(acc[m][n][3] + bs);
                *(ushort4*)(C + gcol * (long)M + grow0) = pk;
            }
        }
    }
}

// ---------------------------------------------------------------------------
// RMSNorm + RoPE + transpose to head-major [nh][S][HD]; one wave per (s,h)
// ---------------------------------------------------------------------------
__global__ __launch_bounds__(256) void norm_rope(const unsigned short* __restrict__ proj,
                                                 int nh,
                                                 const float* __restrict__ w,
                                                 const float* __restrict__ cosT,
                                                 const float* __restrict__ sinT,
                                                 unsigned short* __restrict__ outt,
                                                 float oscale) {
    int wv = (blockIdx.x * 256 + threadIdx.x) >> 6;  // over S*nh
    int lane = threadIdx.x & 63;
    int s = wv / nh, h = wv - s * nh;
    const unsigned short* p = proj + (size_t)s * (nh * HD) + h * HD;
    float x1 = b2f(p[lane]);
    float x2 = b2f(p[lane + 64]);
    float ss = x1 * x1 + x2 * x2;
#pragma unroll
    for (int d = 1; d < 64; d <<= 1) ss += __shfl_xor(ss, d);
    float r = rsqrtf(ss * (1.f / 128.f) + 1e-6f);
    x1 *= r * w[lane];
    x2 *= r * w[lane + 64];
    float cs = cosT[s * 64 + lane], sn = sinT[s * 64 + lane];
    unsigned short o1 = f2b((x1 * cs - x2 * sn) * oscale);
    unsigned short o2 = f2b((x2 * cs + x1 * sn) * oscale);
    unsigned short* q = outt + ((size_t)h * SQ + s) * HD;
    q[lane] = o1;
    q[lane + 64] = o2;
}

// ---------------------------------------------------------------------------
// Causal flash attention v5: v4 design with rule-#20 fix (ALL accumulator
// arrays statically indexed; inactive m handled by wave-uniform branch with
// compile-time m, never by runtime loop bounds).
// Grid 256: h = id&15, qc = id>>4. Wave w: 16 q-rows of chunk qc (m=0) and
// 16 q-rows of chunk 31-qc (m=1). 8 waves, LDS 96KB -> 1 blk/CU, 2 waves/SIMD.
// ---------------------------------------------------------------------------
__global__ __launch_bounds__(512, 2) void fattn(const unsigned short* __restrict__ qt,
                                                const unsigned short* __restrict__ kt,
                                                const unsigned short* __restrict__ vt,
                                                unsigned short* __restrict__ aout) {
    __shared__ unsigned short Ks[2][KVB * HD];   // [64 kv][128 d], key=((row>>2)&7)<<4
    __shared__ unsigned short Vs[2][HD * KVB];   // [128 d][64 kv], key=(row&7)<<4
    __shared__ unsigned short Pl[8][32][64];     // per-wave P, key=(row&7)<<4
    const int tid = threadIdx.x, wid = tid >> 6, lane = tid & 63;
    const int g = lane >> 4, c = lane & 15;
    const int id = blockIdx.x;
    const int h = id & 15, qc = id >> 4, hk = h >> 1;
    const int row0A = qc * 128 + wid * 16;          // m=0 chunk (near)
    const int row0B = (31 - qc) * 128 + wid * 16;   // m=1 chunk (far)
    const unsigned short* qh = qt + (size_t)h * SQ * HD;
    const unsigned short* kh = kt + (size_t)hk * SQ * HD;
    const unsigned short* vh = vt + (size_t)hk * HD * SQ;
    const int ntile = 2 * (31 - qc) + 2;
    char* plw = (char*)&Pl[wid][0][0];

    bf16x8 qa[2][4];
#pragma unroll
    for (int ks = 0; ks < 4; ++ks) {
        qa[0][ks] = *(const bf16x8*)(qh + (size_t)(row0A + c) * HD + ks * 32 + g * 8);
        qa[1][ks] = *(const bf16x8*)(qh + (size_t)(row0B + c) * HD + ks * 32 + g * 8);
    }

    f32x4 o[2][8];
#pragma unroll
    for (int m = 0; m < 2; ++m)
#pragma unroll
        for (int df = 0; df < 8; ++df) o[m][df] = (f32x4){0.f, 0.f, 0.f, 0.f};
    float mrow[2][4], lrow[2][4];
#pragma unroll
    for (int m = 0; m < 2; ++m)
#pragma unroll
        for (int r = 0; r < 4; ++r) { mrow[m][r] = -1e30f; lrow[m][r] = 0.f; }

    auto stage = [&](int b, int t) {
        const int kv0 = t * KVB;
#pragma unroll
        for (int i = 0; i < 2; ++i) {
            const int gi = wid * 2 + i;
            const int P = gi * 1024 + lane * 16;
            const int rk = P >> 8;                                  // K row
            const int Uk = (P & 255) ^ (((rk >> 2) & 7) << 4);
            gload_lds16(kh + (size_t)(kv0 + rk) * HD + (Uk >> 1),
                        (char*)Ks[b] + gi * 1024);
            const int rv = P >> 7;                                  // V row (d)
            const int Uv = (P & 127) ^ ((rv & 7) << 4);
            gload_lds16(vh + (size_t)rv * SQ + kv0 + (Uv >> 1),
                        (char*)Vs[b] + gi * 1024);
        }
    };

    stage(0, 0);
    asm volatile("s_waitcnt vmcnt(0)" ::: "memory");
    __syncthreads();

#define QK_BODY(DO0)                                                          \
    _Pragma("unroll") for (int nf = 0; nf < 4; ++nf) {                        \
        const int krow = (c << 2) + nf;                                       \
        const int key = (c & 7) << 4;                                         \
        _Pragma("unroll") for (int ks = 0; ks < 4; ++ks) {                    \
            bf16x8 kf = *(const bf16x8*)((const char*)Ks[bcur] + krow * 256 + \
                                         ((ks * 64 + g * 16) ^ key));         \
            if (DO0) sa[0][nf] = MFMA16(qa[0][ks], kf, sa[0][nf]);            \
            sa[1][nf] = MFMA16(qa[1][ks], kf, sa[1][nf]);                     \
        }                                                                     \
    }

#define PV_BODY(DO0)                                                          \
    _Pragma("unroll") for (int ks = 0; ks < 2; ++ks) {                        \
        const int pk_ = (ks * 64 + g * 16) ^ ((c & 7) << 4);                  \
        bf16x8 pa1 = *(const bf16x8*)(plw + (16 + c) * 128 + pk_);            \
        bf16x8 pa0{};                                                         \
        if (DO0) pa0 = *(const bf16x8*)(plw + c * 128 + pk_);                 \
        _Pragma("unroll") for (int df = 0; df < 8; ++df) {                    \
            const int rd = df * 16 + c;                                       \
            bf16x8 vb = *(const bf16x8*)((const char*)Vs[bcur] + rd * 128 +   \
                                         ((ks * 64 + g * 16) ^ ((rd & 7) << 4))); \
            if (DO0) o[0][df] = MFMA16(pa0, vb, o[0][df]);                    \
            o[1][df] = MFMA16(pa1, vb, o[1][df]);                             \
        }                                                                     \
    }

    int bcur = 0;
    for (int j = 0; j < ntile; ++j) {
        const int kv0 = j * KVB;
        if (j + 1 < ntile) stage(bcur ^ 1, j + 1);

        const bool act0 = (kv0 <= row0A + 15);   // wave-uniform
        {
            f32x4 sa[2][4];
#pragma unroll
            for (int m = 0; m < 2; ++m)
#pragma unroll
                for (int nf = 0; nf < 4; ++nf) sa[m][nf] = (f32x4){0.f, 0.f, 0.f, 0.f};
            __builtin_amdgcn_s_setprio(1);
            if (act0) { QK_BODY(1) } else { QK_BODY(0) }
            __builtin_amdgcn_s_setprio(0);
            // ---- causal mask (col = kv0 + 4c + nf); static m, uniform branch
#pragma unroll
            for (int m = 0; m < 2; ++m) {
                const int rb = (m == 0) ? row0A : row0B;
                if (m == 0 && !act0) continue;
                if (kv0 + 63 > rb) {
#pragma unroll
                    for (int nf = 0; nf < 4; ++nf) {
                        const int col = kv0 + (c << 2) + nf;
#pragma unroll
                        for (int r = 0; r < 4; ++r) {
                            int row = rb + g * 4 + r;
                            if (col > row) sa[m][nf][r] = -1e30f;
                        }
                    }
                }
            }
            // ---- online softmax (exp2 domain, defer-max); static m everywhere
            float nmax[2][4];
            int small = 1;
#pragma unroll
            for (int m = 0; m < 2; ++m) {
                if (m == 0 && !act0) continue;
#pragma unroll
                for (int r = 0; r < 4; ++r) {
                    float mx = fmaxf(fmaxf(sa[m][0][r], sa[m][1][r]),
                                     fmaxf(sa[m][2][r], sa[m][3][r]));
                    mx = rowmax16(mx);
                    nmax[m][r] = mx;
                    small &= (mx <= mrow[m][r] + 8.0f);
                }
            }
            if (!__all(small)) {
#pragma unroll
                for (int m = 0; m < 2; ++m) {
                    if (m == 0 && !act0) continue;
                    float psc[4];
#pragma unroll
                    for (int r = 0; r < 4; ++r) {
                        float mn = fmaxf(mrow[m][r], nmax[m][r]);
                        psc[r] = __builtin_amdgcn_exp2f(mrow[m][r] - mn);
                        mrow[m][r] = mn;
                        lrow[m][r] *= psc[r];
                    }
#pragma unroll
                    for (int df = 0; df < 8; ++df)
#pragma unroll
                        for (int r = 0; r < 4; ++r) o[m][df][r] *= psc[r];
                }
            }
#pragma unroll
            for (int m = 0; m < 2; ++m) {
                if (m == 0 && !act0) continue;
#pragma unroll
                for (int r = 0; r < 4; ++r) {
                    float rs = 0.f;
#pragma unroll
                    for (int nf = 0; nf < 4; ++nf) {
                        float p = __builtin_amdgcn_exp2f(sa[m][nf][r] - mrow[m][r]);
                        sa[m][nf][r] = p;
                        rs += p;
                    }
                    lrow[m][r] += rowsum16(rs);
                }
            }
            // ---- P -> LDS (cvt_pk + b64, swizzled); static m
#pragma unroll
            for (int m = 0; m < 2; ++m) {
                if (m == 0 && !act0) continue;
#pragma unroll
                for (int r = 0; r < 4; ++r) {
                    unsigned int lo, hi;
                    asm("v_cvt_pk_bf16_f32 %0, %1, %2"
                        : "=v"(lo) : "v"(sa[m][0][r]), "v"(sa[m][1][r]));
                    asm("v_cvt_pk_bf16_f32 %0, %1, %2"
                        : "=v"(hi) : "v"(sa[m][2][r]), "v"(sa[m][3][r]));
                    const int row = m * 16 + g * 4 + r;
                    const int pcol = (c * 8) ^ ((row & 7) << 4);
                    *(uint2*)(plw + row * 128 + pcol) = make_uint2(lo, hi);
                }
            }
            // ---- PV
            __builtin_amdgcn_s_setprio(1);
            if (act0) { PV_BODY(1) } else { PV_BODY(0) }
            __builtin_amdgcn_s_setprio(0);
        }
        asm volatile("s_waitcnt vmcnt(0)" ::: "memory");
        __syncthreads();
        bcur ^= 1;
    }

#pragma unroll
    for (int m = 0; m < 2; ++m) {
        const int rb = (m == 0) ? row0A : row0B;
        float inv[4];
#pragma unroll
        for (int r = 0; r < 4; ++r) inv[r] = 1.f / lrow[m][r];
#pragma unroll
        for (int df = 0; df < 8; ++df)
#pragma unroll
            for (int r = 0; r < 4; ++r) {
                size_t row = rb + g * 4 + r;
                aout[row * QD + h * HD + df * 16 + c] = f2b(o[m][df][r] * inv[r]);
            }
    }
#undef QK_BODY
#undef PV_BODY
}

// ---------------------------------------------------------------------------
extern "C" void kernel_launch(void* const* d_in, const int* in_sizes, int n_in,
                              void* d_out, int out_size, void* d_ws, size_t ws_size,
                              hipStream_t stream) {
    const int*   positions = (const int*)d_in[0];
    const float* hidden    = (const float*)d_in[1];
    const float* wq        = (const float*)d_in[2];
    const float* bq        = (const float*)d_in[3];
    const float* wk        = (const float*)d_in[4];
    const float* bk        = (const float*)d_in[5];
    const float* wv        = (const float*)d_in[6];
    const float* bv        = (const float*)d_in[7];
    const float* wo        = (const float*)d_in[8];
    const float* bo        = (const float*)d_in[9];
    const float* qnw       = (const float*)d_in[10];
    const float* knw       = (const float*)d_in[11];
    float* out = (float*)d_out;

    char* w = (char*)d_ws;
    unsigned short* hidden_b = (unsigned short*)(w);                 // 16 MB
    unsigned short* wq_b     = (unsigned short*)(w + 16777216);      //  8 MB
    unsigned short* wk_b     = (unsigned short*)(w + 25165824);      //  4 MB
    unsigned short* wv_b     = (unsigned short*)(w + 29360128);      //  4 MB
    unsigned short* wo_b     = (unsigned short*)(w + 33554432);      //  8 MB
    unsigned short* qproj    = (unsigned short*)(w + 41943040);      // 16 MB (aliased as attn out)
    unsigned short* kproj    = (unsigned short*)(w + 58720256);      //  8 MB
    unsigned short* q_t      = (unsigned short*)(w + 67108864);      // 16 MB
    unsigned short* k_t      = (unsigned short*)(w + 83886080);      //  8 MB
    unsigned short* v_t      = (unsigned short*)(w + 92274688);      //  8 MB
    float*          cosT     = (float*)(w + 100663296);              //  1 MB
    float*          sinT     = (float*)(w + 101711872);              //  1 MB
    unsigned short* attn     = qproj;  // reuse (qproj consumed before fattn)

    cvt_all<<<20480, 256, 0, stream>>>(hidden, wq, wk, wv, wo,
                                       hidden_b, wq_b, wk_b, wv_b, wo_b);
    rope_table<<<SQ * 64 / 256, 256, 0, stream>>>(positions, cosT, sinT);
    gemm128<0><<<dim3(QD / 128, SQ / 128), 256, 0, stream>>>(hidden_b, wq_b, bq, qproj, SQ, QD, HIDN);
    gemm128<0><<<dim3(KD / 128, SQ / 128), 256, 0, stream>>>(hidden_b, wk_b, bk, kproj, SQ, KD, HIDN);
    gemm128<2><<<dim3(KD / 128, SQ / 128), 256, 0, stream>>>(hidden_b, wv_b, bv, v_t, SQ, KD, HIDN);
    norm_rope<<<SQ * NH / 4, 256, 0, stream>>>(qproj, NH, qnw, cosT, sinT, q_t,
                                               (float)(0.08838834764831845 * 1.4426950408889634));
    norm_rope<<<SQ * NKV / 4, 256, 0, stream>>>(kproj, NKV, knw, cosT, sinT, k_t, 1.0f);
    fattn<<<256, 512, 0, stream>>>(q_t, k_t, v_t, attn);
    gemm128<1><<<dim3(QD / 128, SQ / 128), 256, 0, stream>>>(attn, wo_b, bo, out, SQ, QD, HIDN);
}

// Round 7
// 474.482 us; speedup vs baseline: 2.8488x; 1.0658x over previous
//
#include <hip/hip_runtime.h>
#include <hip/hip_bf16.h>

#define SQ   4096
#define HIDN 2048
#define NH   16
#define NKV  8
#define HD   128
#define QD   2048   // NH*HD
#define KD   1024   // NKV*HD
#define KVB  64

typedef __bf16 bf16x8 __attribute__((ext_vector_type(8)));
typedef float  f32x4  __attribute__((ext_vector_type(4)));

__device__ __forceinline__ float b2f(unsigned short u) {
    union { float f; unsigned int i; } v; v.i = ((unsigned int)u) << 16; return v.f;
}
__device__ __forceinline__ unsigned short f2b(float f) {
    union { float f; unsigned int i; } v; v.f = f;
    unsigned int i = v.i;
    return (unsigned short)((i + 0x7FFFu + ((i >> 16) & 1u)) >> 16);
}

__device__ __forceinline__ void gload_lds16(const void* g, void* l) {
    __builtin_amdgcn_global_load_lds(
        (const __attribute__((address_space(1))) unsigned int*)g,
        (__attribute__((address_space(3))) unsigned int*)l, 16, 0, 0);
}

#define MFMA16(a, b, c) __builtin_amdgcn_mfma_f32_16x16x32_bf16(a, b, c, 0, 0, 0)

// DPP row-rotate (within 16-lane rows) for cross-lane reduce on the VALU pipe.
#define DPP_ROR(x, n) __int_as_float(__builtin_amdgcn_update_dpp(            \
    __float_as_int(x), __float_as_int(x), 0x120 + (n), 0xF, 0xF, false))

__device__ __forceinline__ float rowmax16(float x) {
    x = fmaxf(x, DPP_ROR(x, 1));
    x = fmaxf(x, DPP_ROR(x, 2));
    x = fmaxf(x, DPP_ROR(x, 4));
    x = fmaxf(x, DPP_ROR(x, 8));
    return x;
}
__device__ __forceinline__ float rowsum16(float x) {
    x += DPP_ROR(x, 1);
    x += DPP_ROR(x, 2);
    x += DPP_ROR(x, 4);
    x += DPP_ROR(x, 8);
    return x;
}

// ---------------------------------------------------------------------------
// merged f32 -> bf16 convert for all 5 tensors (one launch)
// ---------------------------------------------------------------------------
__global__ __launch_bounds__(256) void cvt_all(const float* __restrict__ h,
                                               const float* __restrict__ wq,
                                               const float* __restrict__ wk,
                                               const float* __restrict__ wv,
                                               const float* __restrict__ wo,
                                               unsigned short* __restrict__ oh,
                                               unsigned short* __restrict__ owq,
                                               unsigned short* __restrict__ owk,
                                               unsigned short* __restrict__ owv,
                                               unsigned short* __restrict__ owo) {
    int i = blockIdx.x * 256 + threadIdx.x;  // float4 index, 5M total
    const float* src; unsigned short* dst; int off;
    if (i < 2097152)      { src = h;  dst = oh;  off = i; }
    else if (i < 3145728) { src = wq; dst = owq; off = i - 2097152; }
    else if (i < 3670016) { src = wk; dst = owk; off = i - 3145728; }
    else if (i < 4194304) { src = wv; dst = owv; off = i - 3670016; }
    else                  { src = wo; dst = owo; off = i - 4194304; }
    float4 v = ((const float4*)src)[off];
    ushort4 u;
    u.x = f2b(v.x); u.y = f2b(v.y); u.z = f2b(v.z); u.w = f2b(v.w);
    ((ushort4*)dst)[off] = u;
}

// ---------------------------------------------------------------------------
// RoPE cos/sin table: [S][64] each
// ---------------------------------------------------------------------------
__global__ __launch_bounds__(256) void rope_table(const int* __restrict__ pos,
                                                  float* __restrict__ cosT,
                                                  float* __restrict__ sinT) {
    int i = blockIdx.x * 256 + threadIdx.x;  // S*64 total
    int s = i >> 6, j = i & 63;
    float invf = __expf(-(float)j * (1.3815510557964274f / 6.4f));  // ln(1e6)/64
    float a = (float)pos[s] * invf;
    cosT[i] = cosf(a);
    sinT[i] = sinf(a);
}

// ---------------------------------------------------------------------------
// Fused QKV GEMM: C[4096][4096] = A[4096][2048] @ B[4096][2048]^T, where
// B = wq (rows 0..2047) || wk (2048..3071) || wv (3072..4095), contiguous.
// Epilogue routes: cols<2048 -> qproj bf16 [S][QD]; <3072 -> kproj [S][KD];
// else -> v_t transposed [(col-3072)][S] bf16. Grid (32,32) = 1024 blocks.
// ---------------------------------------------------------------------------
__global__ __launch_bounds__(256) void gemm_qkv(const unsigned short* __restrict__ A,
                                                const unsigned short* __restrict__ B,
                                                const float* __restrict__ bq,
                                                const float* __restrict__ bk,
                                                const float* __restrict__ bv,
                                                unsigned short* __restrict__ qp,
                                                unsigned short* __restrict__ kp,
                                                unsigned short* __restrict__ vtp) {
    const int M = 4096, K = 2048;
    __shared__ unsigned short As[128 * 32];
    __shared__ unsigned short Bs[128 * 32];
    const int tid = threadIdx.x, wid = tid >> 6, lane = tid & 63;
    const int g = lane >> 4, c = lane & 15;
    const int wr = wid >> 1, wc = wid & 1;
    const int orig = blockIdx.y * gridDim.x + blockIdx.x;
    const int cpx = (gridDim.x * gridDim.y) >> 3;
    const int wg = (orig & 7) * cpx + (orig >> 3);
    const int bx = wg % gridDim.x, by = wg / gridDim.x;
    const long rowbase = (long)by * 128;
    const long colbase = (long)bx * 128;

    f32x4 acc[4][4];
#pragma unroll
    for (int m = 0; m < 4; ++m)
#pragma unroll
        for (int n = 0; n < 4; ++n) acc[m][n] = (f32x4){0.f, 0.f, 0.f, 0.f};

    const int ch0 = (wid * 2) * 64 + lane;
    const int ch1 = (wid * 2 + 1) * 64 + lane;

    for (int kt = 0; kt < K; kt += 32) {
        gload_lds16(A + ((rowbase + (ch0 >> 2)) * K + kt + (ch0 & 3) * 8),
                    As + (wid * 2) * 64 * 8);
        gload_lds16(B + ((colbase + (ch0 >> 2)) * K + kt + (ch0 & 3) * 8),
                    Bs + (wid * 2) * 64 * 8);
        gload_lds16(A + ((rowbase + (ch1 >> 2)) * K + kt + (ch1 & 3) * 8),
                    As + (wid * 2 + 1) * 64 * 8);
        gload_lds16(B + ((colbase + (ch1 >> 2)) * K + kt + (ch1 & 3) * 8),
                    Bs + (wid * 2 + 1) * 64 * 8);
        __syncthreads();
        bf16x8 a[4], b[4];
#pragma unroll
        for (int m = 0; m < 4; ++m)
            a[m] = *(const bf16x8*)(As + (wr * 64 + m * 16 + c) * 32 + g * 8);
#pragma unroll
        for (int n = 0; n < 4; ++n)
            b[n] = *(const bf16x8*)(Bs + (wc * 64 + n * 16 + c) * 32 + g * 8);
#pragma unroll
        for (int m = 0; m < 4; ++m)
#pragma unroll
            for (int n = 0; n < 4; ++n) acc[m][n] = MFMA16(a[m], b[n], acc[m][n]);
        __syncthreads();
    }

#pragma unroll
    for (int m = 0; m < 4; ++m) {
        const long grow0 = rowbase + wr * 64 + m * 16 + g * 4;
#pragma unroll
        for (int n = 0; n < 4; ++n) {
            const long gcol = colbase + wc * 64 + n * 16 + c;
            if (colbase < 2048) {
                const float bs = bq[gcol];
#pragma unroll
                for (int r = 0; r < 4; ++r)
                    qp[(grow0 + r) * QD + gcol] = f2b(acc[m][n][r] + bs);
            } else if (colbase < 3072) {
                const float bs = bk[gcol - 2048];
#pragma unroll
                for (int r = 0; r < 4; ++r)
                    kp[(grow0 + r) * KD + (gcol - 2048)] = f2b(acc[m][n][r] + bs);
            } else {
                const float bs = bv[gcol - 3072];
                ushort4 pk;
                pk.x = f2b(acc[m][n][0] + bs);
                pk.y = f2b(acc[m][n][1] + bs);
                pk.z = f2b(acc[m][n][2] + bs);
                pk.w = f2b(acc[m][n][3] + bs);
                *(ushort4*)(vtp + (gcol - 3072) * (long)M + grow0) = pk;
            }
        }
    }
}

// ---------------------------------------------------------------------------
// O-projection GEMM: C[M][N] f32 = A[M][K] @ B[N][K]^T + bias
// ---------------------------------------------------------------------------
__global__ __launch_bounds__(256) void gemm_o(const unsigned short* __restrict__ A,
                                              const unsigned short* __restrict__ B,
                                              const float* __restrict__ bias,
                                              float* __restrict__ Cout,
                                              int M, int N, int K) {
    __shared__ unsigned short As[128 * 32];
    __shared__ unsigned short Bs[128 * 32];
    const int tid = threadIdx.x, wid = tid >> 6, lane = tid & 63;
    const int g = lane >> 4, c = lane & 15;
    const int wr = wid >> 1, wc = wid & 1;
    const int orig = blockIdx.y * gridDim.x + blockIdx.x;
    const int cpx = (gridDim.x * gridDim.y) >> 3;
    const int wg = (orig & 7) * cpx + (orig >> 3);
    const int bx = wg % gridDim.x, by = wg / gridDim.x;
    const long rowbase = (long)by * 128;
    const long colbase = (long)bx * 128;

    f32x4 acc[4][4];
#pragma unroll
    for (int m = 0; m < 4; ++m)
#pragma unroll
        for (int n = 0; n < 4; ++n) acc[m][n] = (f32x4){0.f, 0.f, 0.f, 0.f};

    const int ch0 = (wid * 2) * 64 + lane;
    const int ch1 = (wid * 2 + 1) * 64 + lane;

    for (int kt = 0; kt < K; kt += 32) {
        gload_lds16(A + ((rowbase + (ch0 >> 2)) * K + kt + (ch0 & 3) * 8),
                    As + (wid * 2) * 64 * 8);
        gload_lds16(B + ((colbase + (ch0 >> 2)) * K + kt + (ch0 & 3) * 8),
                    Bs + (wid * 2) * 64 * 8);
        gload_lds16(A + ((rowbase + (ch1 >> 2)) * K + kt + (ch1 & 3) * 8),
                    As + (wid * 2 + 1) * 64 * 8);
        gload_lds16(B + ((colbase + (ch1 >> 2)) * K + kt + (ch1 & 3) * 8),
                    Bs + (wid * 2 + 1) * 64 * 8);
        __syncthreads();
        bf16x8 a[4], b[4];
#pragma unroll
        for (int m = 0; m < 4; ++m)
            a[m] = *(const bf16x8*)(As + (wr * 64 + m * 16 + c) * 32 + g * 8);
#pragma unroll
        for (int n = 0; n < 4; ++n)
            b[n] = *(const bf16x8*)(Bs + (wc * 64 + n * 16 + c) * 32 + g * 8);
#pragma unroll
        for (int m = 0; m < 4; ++m)
#pragma unroll
            for (int n = 0; n < 4; ++n) acc[m][n] = MFMA16(a[m], b[n], acc[m][n]);
        __syncthreads();
    }

#pragma unroll
    for (int m = 0; m < 4; ++m) {
        const long grow0 = rowbase + wr * 64 + m * 16 + g * 4;
#pragma unroll
        for (int n = 0; n < 4; ++n) {
            const long gcol = colbase + wc * 64 + n * 16 + c;
            const float bs = bias[gcol];
#pragma unroll
            for (int r = 0; r < 4; ++r)
                Cout[(grow0 + r) * N + gcol] = acc[m][n][r] + bs;
        }
    }
}

// ---------------------------------------------------------------------------
// RMSNorm + RoPE + transpose to head-major [nh][S][HD]; one wave per (s,h)
// ---------------------------------------------------------------------------
__global__ __launch_bounds__(256) void norm_rope(const unsigned short* __restrict__ proj,
                                                 int nh,
                                                 const float* __restrict__ w,
                                                 const float* __restrict__ cosT,
                                                 const float* __restrict__ sinT,
                                                 unsigned short* __restrict__ outt,
                                                 float oscale) {
    int wv = (blockIdx.x * 256 + threadIdx.x) >> 6;  // over S*nh
    int lane = threadIdx.x & 63;
    int s = wv / nh, h = wv - s * nh;
    const unsigned short* p = proj + (size_t)s * (nh * HD) + h * HD;
    float x1 = b2f(p[lane]);
    float x2 = b2f(p[lane + 64]);
    float ss = x1 * x1 + x2 * x2;
#pragma unroll
    for (int d = 1; d < 64; d <<= 1) ss += __shfl_xor(ss, d);
    float r = rsqrtf(ss * (1.f / 128.f) + 1e-6f);
    x1 *= r * w[lane];
    x2 *= r * w[lane + 64];
    float cs = cosT[s * 64 + lane], sn = sinT[s * 64 + lane];
    unsigned short o1 = f2b((x1 * cs - x2 * sn) * oscale);
    unsigned short o2 = f2b((x2 * cs + x1 * sn) * oscale);
    unsigned short* q = outt + ((size_t)h * SQ + s) * HD;
    q[lane] = o1;
    q[lane + 64] = o2;
}

// ---------------------------------------------------------------------------
// Causal flash attention v6: grid 512 x 4 waves, one 128-row chunk per block,
// 32 always-active q-rows per wave (2 m-frags), 2 independent blocks/CU.
// Complementary dispatch: block i and i+256 -> (qb, 31-qb) on the same CU
// (perf heuristic only). LDS 64KB: K/V double-buffered; per-wave P buffer
// aliased into the DEAD K tile (K[bcur] after QK) -- guarded by a lgkm-only
// mid-tile s_barrier (NOT __syncthreads: must not drain vmcnt/prefetch).
// qt: [NH][S][HD] pre-scaled by scale*log2e; kt: [NKV][S][HD]; vt: [NKV][HD][S]
// ---------------------------------------------------------------------------
__global__ __launch_bounds__(256, 2) void fattn(const unsigned short* __restrict__ qt,
                                                const unsigned short* __restrict__ kt,
                                                const unsigned short* __restrict__ vt,
                                                unsigned short* __restrict__ aout) {
    __shared__ unsigned short Ks[2][KVB * HD];   // [64 kv][128 d], key=((row>>2)&7)<<4
    __shared__ unsigned short Vs[2][HD * KVB];   // [128 d][64 kv], key=(row&7)<<4
    const int tid = threadIdx.x, wid = tid >> 6, lane = tid & 63;
    const int g = lane >> 4, c = lane & 15;
    const int id = blockIdx.x;
    const int qb = (id < 256) ? (31 - (id >> 4)) : ((id - 256) >> 4);
    const int h = id & 15, hk = h >> 1;
    const int row0 = qb * 128 + wid * 32;
    const unsigned short* qh = qt + (size_t)h * SQ * HD;
    const unsigned short* kh = kt + (size_t)hk * SQ * HD;
    const unsigned short* vh = vt + (size_t)hk * HD * SQ;
    const int ntile = 2 * qb + 2;

    bf16x8 qa[2][4];
#pragma unroll
    for (int ks = 0; ks < 4; ++ks) {
        qa[0][ks] = *(const bf16x8*)(qh + (size_t)(row0 + c) * HD + ks * 32 + g * 8);
        qa[1][ks] = *(const bf16x8*)(qh + (size_t)(row0 + 16 + c) * HD + ks * 32 + g * 8);
    }

    f32x4 o[2][8];
#pragma unroll
    for (int m = 0; m < 2; ++m)
#pragma unroll
        for (int df = 0; df < 8; ++df) o[m][df] = (f32x4){0.f, 0.f, 0.f, 0.f};
    float mrow[2][4], lrow[2][4];
#pragma unroll
    for (int m = 0; m < 2; ++m)
#pragma unroll
        for (int r = 0; r < 4; ++r) { mrow[m][r] = -1e30f; lrow[m][r] = 0.f; }

    // staging: 16 x 1KB granules per tensor, 4 waves take 4 of each
    auto stage = [&](int b, int t) {
        const int kv0 = t * KVB;
#pragma unroll
        for (int i = 0; i < 4; ++i) {
            const int gi = wid * 4 + i;
            const int P = gi * 1024 + lane * 16;
            const int rk = P >> 8;                                  // K row
            const int Uk = (P & 255) ^ (((rk >> 2) & 7) << 4);
            gload_lds16(kh + (size_t)(kv0 + rk) * HD + (Uk >> 1),
                        (char*)Ks[b] + gi * 1024);
            const int rv = P >> 7;                                  // V row (d)
            const int Uv = (P & 127) ^ ((rv & 7) << 4);
            gload_lds16(vh + (size_t)rv * SQ + kv0 + (Uv >> 1),
                        (char*)Vs[b] + gi * 1024);
        }
    };

    stage(0, 0);
    asm volatile("s_waitcnt vmcnt(0)" ::: "memory");
    __syncthreads();

    int bcur = 0;
    for (int j = 0; j < ntile; ++j) {
        const int kv0 = j * KVB;
        if (j + 1 < ntile) stage(bcur ^ 1, j + 1);

        // ---- QK^T (kv = 4*c + nf); both m always active
        f32x4 sa[2][4];
#pragma unroll
        for (int m = 0; m < 2; ++m)
#pragma unroll
            for (int nf = 0; nf < 4; ++nf) sa[m][nf] = (f32x4){0.f, 0.f, 0.f, 0.f};
        __builtin_amdgcn_s_setprio(1);
#pragma unroll
        for (int nf = 0; nf < 4; ++nf) {
            const int krow = (c << 2) + nf;
            const int key = (c & 7) << 4;  // == ((krow>>2)&7)<<4
#pragma unroll
            for (int ks = 0; ks < 4; ++ks) {
                bf16x8 kf = *(const bf16x8*)((const char*)Ks[bcur] + krow * 256 +
                                             ((ks * 64 + g * 16) ^ key));
                sa[0][nf] = MFMA16(qa[0][ks], kf, sa[0][nf]);
                sa[1][nf] = MFMA16(qa[1][ks], kf, sa[1][nf]);
            }
        }
        __builtin_amdgcn_s_setprio(0);
        // ---- retire K[bcur]: every wave's K reads done -> safe to reuse as P.
        // lgkm-only drain + raw barrier (vmcnt prefetch stays in flight).
        asm volatile("s_waitcnt lgkmcnt(0)" ::: "memory");
        __builtin_amdgcn_s_barrier();
        char* plw = (char*)Ks[bcur] + wid * 4096;   // 32 rows x 128B per wave

        // ---- causal mask (col = kv0 + 4c + nf); only near the diagonal
        if (kv0 + 63 > row0) {
#pragma unroll
            for (int m = 0; m < 2; ++m) {
                const int rb = row0 + m * 16;
#pragma unroll
                for (int nf = 0; nf < 4; ++nf) {
                    const int col = kv0 + (c << 2) + nf;
#pragma unroll
                    for (int r = 0; r < 4; ++r) {
                        int row = rb + g * 4 + r;
                        if (col > row) sa[m][nf][r] = -1e30f;
                    }
                }
            }
        }
        // ---- online softmax in exp2 domain, defer-max (T13)
        float nmax[2][4];
        int small = 1;
#pragma unroll
        for (int m = 0; m < 2; ++m)
#pragma unroll
            for (int r = 0; r < 4; ++r) {
                float mx = fmaxf(fmaxf(sa[m][0][r], sa[m][1][r]),
                                 fmaxf(sa[m][2][r], sa[m][3][r]));
                mx = rowmax16(mx);
                nmax[m][r] = mx;
                small &= (mx <= mrow[m][r] + 8.0f);
            }
        if (!__all(small)) {
#pragma unroll
            for (int m = 0; m < 2; ++m) {
                float psc[4];
#pragma unroll
                for (int r = 0; r < 4; ++r) {
                    float mn = fmaxf(mrow[m][r], nmax[m][r]);
                    psc[r] = __builtin_amdgcn_exp2f(mrow[m][r] - mn);
                    mrow[m][r] = mn;
                    lrow[m][r] *= psc[r];
                }
#pragma unroll
                for (int df = 0; df < 8; ++df)
#pragma unroll
                    for (int r = 0; r < 4; ++r) o[m][df][r] *= psc[r];
            }
        }
#pragma unroll
        for (int m = 0; m < 2; ++m)
#pragma unroll
            for (int r = 0; r < 4; ++r) {
                float rs = 0.f;
#pragma unroll
                for (int nf = 0; nf < 4; ++nf) {
                    float p = __builtin_amdgcn_exp2f(sa[m][nf][r] - mrow[m][r]);
                    sa[m][nf][r] = p;
                    rs += p;
                }
                lrow[m][r] += rowsum16(rs);
            }
        // ---- P -> LDS (cvt_pk + b64, swizzled), into dead K region
#pragma unroll
        for (int m = 0; m < 2; ++m)
#pragma unroll
            for (int r = 0; r < 4; ++r) {
                unsigned int lo, hi;
                asm("v_cvt_pk_bf16_f32 %0, %1, %2"
                    : "=v"(lo) : "v"(sa[m][0][r]), "v"(sa[m][1][r]));
                asm("v_cvt_pk_bf16_f32 %0, %1, %2"
                    : "=v"(hi) : "v"(sa[m][2][r]), "v"(sa[m][3][r]));
                const int row = m * 16 + g * 4 + r;
                const int pcol = (c * 8) ^ ((row & 7) << 4);
                *(uint2*)(plw + row * 128 + pcol) = make_uint2(lo, hi);
            }
        asm volatile("s_waitcnt lgkmcnt(0)" ::: "memory");
        // ---- PV
        __builtin_amdgcn_s_setprio(1);
#pragma unroll
        for (int ks = 0; ks < 2; ++ks) {
            const int pk_ = (ks * 64 + g * 16) ^ ((c & 7) << 4);
            bf16x8 pa0 = *(const bf16x8*)(plw + c * 128 + pk_);
            bf16x8 pa1 = *(const bf16x8*)(plw + (16 + c) * 128 + pk_);
#pragma unroll
            for (int df = 0; df < 8; ++df) {
                const int rd = df * 16 + c;
                bf16x8 vb = *(const bf16x8*)((const char*)Vs[bcur] + rd * 128 +
                                             ((ks * 64 + g * 16) ^ ((rd & 7) << 4)));
                o[0][df] = MFMA16(pa0, vb, o[0][df]);
                o[1][df] = MFMA16(pa1, vb, o[1][df]);
            }
        }
        __builtin_amdgcn_s_setprio(0);

        asm volatile("s_waitcnt vmcnt(0)" ::: "memory");
        __syncthreads();
        bcur ^= 1;
    }

#pragma unroll
    for (int m = 0; m < 2; ++m) {
        const int rb = row0 + m * 16;
        float inv[4];
#pragma unroll
        for (int r = 0; r < 4; ++r) inv[r] = 1.f / lrow[m][r];
#pragma unroll
        for (int df = 0; df < 8; ++df)
#pragma unroll
            for (int r = 0; r < 4; ++r) {
                size_t row = rb + g * 4 + r;
                aout[row * QD + h * HD + df * 16 + c] = f2b(o[m][df][r] * inv[r]);
            }
    }
}

// ---------------------------------------------------------------------------
extern "C" void kernel_launch(void* const* d_in, const int* in_sizes, int n_in,
                              void* d_out, int out_size, void* d_ws, size_t ws_size,
                              hipStream_t stream) {
    const int*   positions = (const int*)d_in[0];
    const float* hidden    = (const float*)d_in[1];
    const float* wq        = (const float*)d_in[2];
    const float* bq        = (const float*)d_in[3];
    const float* wk        = (const float*)d_in[4];
    const float* bk        = (const float*)d_in[5];
    const float* wv        = (const float*)d_in[6];
    const float* bv        = (const float*)d_in[7];
    const float* wo        = (const float*)d_in[8];
    const float* bo        = (const float*)d_in[9];
    const float* qnw       = (const float*)d_in[10];
    const float* knw       = (const float*)d_in[11];
    float* out = (float*)d_out;

    char* w = (char*)d_ws;
    unsigned short* hidden_b = (unsigned short*)(w);                 // 16 MB
    unsigned short* wqkv_b   = (unsigned short*)(w + 16777216);      // 16 MB total:
    unsigned short* wq_b     = (unsigned short*)(w + 16777216);      //   wq 8 MB
    unsigned short* wk_b     = (unsigned short*)(w + 25165824);      //   wk 4 MB
    unsigned short* wv_b     = (unsigned short*)(w + 29360128);      //   wv 4 MB
    unsigned short* wo_b     = (unsigned short*)(w + 33554432);      //  8 MB
    unsigned short* qproj    = (unsigned short*)(w + 41943040);      // 16 MB (aliased as attn out)
    unsigned short* kproj    = (unsigned short*)(w + 58720256);      //  8 MB
    unsigned short* q_t      = (unsigned short*)(w + 67108864);      // 16 MB
    unsigned short* k_t      = (unsigned short*)(w + 83886080);      //  8 MB
    unsigned short* v_t      = (unsigned short*)(w + 92274688);      //  8 MB
    float*          cosT     = (float*)(w + 100663296);              //  1 MB
    float*          sinT     = (float*)(w + 101711872);              //  1 MB
    unsigned short* attn     = qproj;  // reuse (qproj consumed before fattn)

    cvt_all<<<20480, 256, 0, stream>>>(hidden, wq, wk, wv, wo,
                                       hidden_b, wq_b, wk_b, wv_b, wo_b);
    rope_table<<<SQ * 64 / 256, 256, 0, stream>>>(positions, cosT, sinT);
    // fused QKV projection (B = wq||wk||wv contiguous)
    gemm_qkv<<<dim3(32, 32), 256, 0, stream>>>(hidden_b, wqkv_b, bq, bk, bv,
                                               qproj, kproj, v_t);
    norm_rope<<<SQ * NH / 4, 256, 0, stream>>>(qproj, NH, qnw, cosT, sinT, q_t,
                                               (float)(0.08838834764831845 * 1.4426950408889634));
    norm_rope<<<SQ * NKV / 4, 256, 0, stream>>>(kproj, NKV, knw, cosT, sinT, k_t, 1.0f);
    fattn<<<512, 256, 0, stream>>>(q_t, k_t, v_t, attn);
    gemm_o<<<dim3(QD / 128, SQ / 128), 256, 0, stream>>>(attn, wo_b, bo, out, SQ, QD, HIDN);
}

// Round 8
// 454.411 us; speedup vs baseline: 2.9747x; 1.0442x over previous
//
#include <hip/hip_runtime.h>
#include <hip/hip_bf16.h>

#define SQ   4096
#define HIDN 2048
#define NH   16
#define NKV  8
#define HD   128
#define QD   2048   // NH*HD
#define KD   1024   // NKV*HD
#define KVB  64

typedef __bf16 bf16x8 __attribute__((ext_vector_type(8)));
typedef float  f32x4  __attribute__((ext_vector_type(4)));

__device__ __forceinline__ float b2f(unsigned short u) {
    union { float f; unsigned int i; } v; v.i = ((unsigned int)u) << 16; return v.f;
}
__device__ __forceinline__ unsigned short f2b(float f) {
    union { float f; unsigned int i; } v; v.f = f;
    unsigned int i = v.i;
    return (unsigned short)((i + 0x7FFFu + ((i >> 16) & 1u)) >> 16);
}

__device__ __forceinline__ void gload_lds16(const void* g, void* l) {
    __builtin_amdgcn_global_load_lds(
        (const __attribute__((address_space(1))) unsigned int*)g,
        (__attribute__((address_space(3))) unsigned int*)l, 16, 0, 0);
}

#define MFMA16(a, b, c) __builtin_amdgcn_mfma_f32_16x16x32_bf16(a, b, c, 0, 0, 0)

// DPP row-rotate (within 16-lane rows) for cross-lane reduce on the VALU pipe.
#define DPP_ROR(x, n) __int_as_float(__builtin_amdgcn_update_dpp(            \
    __float_as_int(x), __float_as_int(x), 0x120 + (n), 0xF, 0xF, false))

__device__ __forceinline__ float rowmax16(float x) {
    x = fmaxf(x, DPP_ROR(x, 1));
    x = fmaxf(x, DPP_ROR(x, 2));
    x = fmaxf(x, DPP_ROR(x, 4));
    x = fmaxf(x, DPP_ROR(x, 8));
    return x;
}
__device__ __forceinline__ float rowsum16(float x) {
    x += DPP_ROR(x, 1);
    x += DPP_ROR(x, 2);
    x += DPP_ROR(x, 4);
    x += DPP_ROR(x, 8);
    return x;
}

// ---------------------------------------------------------------------------
// merged f32 -> bf16 convert for all 5 tensors (one launch)
// ---------------------------------------------------------------------------
__global__ __launch_bounds__(256) void cvt_all(const float* __restrict__ h,
                                               const float* __restrict__ wq,
                                               const float* __restrict__ wk,
                                               const float* __restrict__ wv,
                                               const float* __restrict__ wo,
                                               unsigned short* __restrict__ oh,
                                               unsigned short* __restrict__ owq,
                                               unsigned short* __restrict__ owk,
                                               unsigned short* __restrict__ owv,
                                               unsigned short* __restrict__ owo) {
    int i = blockIdx.x * 256 + threadIdx.x;  // float4 index, 5M total
    const float* src; unsigned short* dst; int off;
    if (i < 2097152)      { src = h;  dst = oh;  off = i; }
    else if (i < 3145728) { src = wq; dst = owq; off = i - 2097152; }
    else if (i < 3670016) { src = wk; dst = owk; off = i - 3145728; }
    else if (i < 4194304) { src = wv; dst = owv; off = i - 3670016; }
    else                  { src = wo; dst = owo; off = i - 4194304; }
    float4 v = ((const float4*)src)[off];
    ushort4 u;
    u.x = f2b(v.x); u.y = f2b(v.y); u.z = f2b(v.z); u.w = f2b(v.w);
    ((ushort4*)dst)[off] = u;
}

// ---------------------------------------------------------------------------
// RoPE cos/sin table: [S][64] each
// ---------------------------------------------------------------------------
__global__ __launch_bounds__(256) void rope_table(const int* __restrict__ pos,
                                                  float* __restrict__ cosT,
                                                  float* __restrict__ sinT) {
    int i = blockIdx.x * 256 + threadIdx.x;  // S*64 total
    int s = i >> 6, j = i & 63;
    float invf = __expf(-(float)j * (1.3815510557964274f / 6.4f));  // ln(1e6)/64
    float a = (float)pos[s] * invf;
    cosT[i] = cosf(a);
    sinT[i] = sinf(a);
}

// ---------------------------------------------------------------------------
// Fused QKV GEMM: C[4096][4096] = A[4096][2048] @ B[4096][2048]^T, where
// B = wq || wk || wv contiguous. Epilogue routes q/k/v (v transposed).
// ---------------------------------------------------------------------------
__global__ __launch_bounds__(256) void gemm_qkv(const unsigned short* __restrict__ A,
                                                const unsigned short* __restrict__ B,
                                                const float* __restrict__ bq,
                                                const float* __restrict__ bk,
                                                const float* __restrict__ bv,
                                                unsigned short* __restrict__ qp,
                                                unsigned short* __restrict__ kp,
                                                unsigned short* __restrict__ vtp) {
    const int M = 4096, K = 2048;
    __shared__ unsigned short As[128 * 32];
    __shared__ unsigned short Bs[128 * 32];
    const int tid = threadIdx.x, wid = tid >> 6, lane = tid & 63;
    const int g = lane >> 4, c = lane & 15;
    const int wr = wid >> 1, wc = wid & 1;
    const int orig = blockIdx.y * gridDim.x + blockIdx.x;
    const int cpx = (gridDim.x * gridDim.y) >> 3;
    const int wg = (orig & 7) * cpx + (orig >> 3);
    const int bx = wg % gridDim.x, by = wg / gridDim.x;
    const long rowbase = (long)by * 128;
    const long colbase = (long)bx * 128;

    f32x4 acc[4][4];
#pragma unroll
    for (int m = 0; m < 4; ++m)
#pragma unroll
        for (int n = 0; n < 4; ++n) acc[m][n] = (f32x4){0.f, 0.f, 0.f, 0.f};

    const int ch0 = (wid * 2) * 64 + lane;
    const int ch1 = (wid * 2 + 1) * 64 + lane;

    for (int kt = 0; kt < K; kt += 32) {
        gload_lds16(A + ((rowbase + (ch0 >> 2)) * K + kt + (ch0 & 3) * 8),
                    As + (wid * 2) * 64 * 8);
        gload_lds16(B + ((colbase + (ch0 >> 2)) * K + kt + (ch0 & 3) * 8),
                    Bs + (wid * 2) * 64 * 8);
        gload_lds16(A + ((rowbase + (ch1 >> 2)) * K + kt + (ch1 & 3) * 8),
                    As + (wid * 2 + 1) * 64 * 8);
        gload_lds16(B + ((colbase + (ch1 >> 2)) * K + kt + (ch1 & 3) * 8),
                    Bs + (wid * 2 + 1) * 64 * 8);
        __syncthreads();
        bf16x8 a[4], b[4];
#pragma unroll
        for (int m = 0; m < 4; ++m)
            a[m] = *(const bf16x8*)(As + (wr * 64 + m * 16 + c) * 32 + g * 8);
#pragma unroll
        for (int n = 0; n < 4; ++n)
            b[n] = *(const bf16x8*)(Bs + (wc * 64 + n * 16 + c) * 32 + g * 8);
#pragma unroll
        for (int m = 0; m < 4; ++m)
#pragma unroll
            for (int n = 0; n < 4; ++n) acc[m][n] = MFMA16(a[m], b[n], acc[m][n]);
        __syncthreads();
    }

#pragma unroll
    for (int m = 0; m < 4; ++m) {
        const long grow0 = rowbase + wr * 64 + m * 16 + g * 4;
#pragma unroll
        for (int n = 0; n < 4; ++n) {
            const long gcol = colbase + wc * 64 + n * 16 + c;
            if (colbase < 2048) {
                const float bs = bq[gcol];
#pragma unroll
                for (int r = 0; r < 4; ++r)
                    qp[(grow0 + r) * QD + gcol] = f2b(acc[m][n][r] + bs);
            } else if (colbase < 3072) {
                const float bs = bk[gcol - 2048];
#pragma unroll
                for (int r = 0; r < 4; ++r)
                    kp[(grow0 + r) * KD + (gcol - 2048)] = f2b(acc[m][n][r] + bs);
            } else {
                const float bs = bv[gcol - 3072];
                ushort4 pk;
                pk.x = f2b(acc[m][n][0] + bs);
                pk.y = f2b(acc[m][n][1] + bs);
                pk.z = f2b(acc[m][n][2] + bs);
                pk.w = f2b(acc[m][n][3] + bs);
                *(ushort4*)(vtp + (gcol - 3072) * (long)M + grow0) = pk;
            }
        }
    }
}

// ---------------------------------------------------------------------------
// O-projection GEMM: C[M][N] f32 = A[M][K] @ B[N][K]^T + bias
// ---------------------------------------------------------------------------
__global__ __launch_bounds__(256) void gemm_o(const unsigned short* __restrict__ A,
                                              const unsigned short* __restrict__ B,
                                              const float* __restrict__ bias,
                                              float* __restrict__ Cout,
                                              int M, int N, int K) {
    __shared__ unsigned short As[128 * 32];
    __shared__ unsigned short Bs[128 * 32];
    const int tid = threadIdx.x, wid = tid >> 6, lane = tid & 63;
    const int g = lane >> 4, c = lane & 15;
    const int wr = wid >> 1, wc = wid & 1;
    const int orig = blockIdx.y * gridDim.x + blockIdx.x;
    const int cpx = (gridDim.x * gridDim.y) >> 3;
    const int wg = (orig & 7) * cpx + (orig >> 3);
    const int bx = wg % gridDim.x, by = wg / gridDim.x;
    const long rowbase = (long)by * 128;
    const long colbase = (long)bx * 128;

    f32x4 acc[4][4];
#pragma unroll
    for (int m = 0; m < 4; ++m)
#pragma unroll
        for (int n = 0; n < 4; ++n) acc[m][n] = (f32x4){0.f, 0.f, 0.f, 0.f};

    const int ch0 = (wid * 2) * 64 + lane;
    const int ch1 = (wid * 2 + 1) * 64 + lane;

    for (int kt = 0; kt < K; kt += 32) {
        gload_lds16(A + ((rowbase + (ch0 >> 2)) * K + kt + (ch0 & 3) * 8),
                    As + (wid * 2) * 64 * 8);
        gload_lds16(B + ((colbase + (ch0 >> 2)) * K + kt + (ch0 & 3) * 8),
                    Bs + (wid * 2) * 64 * 8);
        gload_lds16(A + ((rowbase + (ch1 >> 2)) * K + kt + (ch1 & 3) * 8),
                    As + (wid * 2 + 1) * 64 * 8);
        gload_lds16(B + ((colbase + (ch1 >> 2)) * K + kt + (ch1 & 3) * 8),
                    Bs + (wid * 2 + 1) * 64 * 8);
        __syncthreads();
        bf16x8 a[4], b[4];
#pragma unroll
        for (int m = 0; m < 4; ++m)
            a[m] = *(const bf16x8*)(As + (wr * 64 + m * 16 + c) * 32 + g * 8);
#pragma unroll
        for (int n = 0; n < 4; ++n)
            b[n] = *(const bf16x8*)(Bs + (wc * 64 + n * 16 + c) * 32 + g * 8);
#pragma unroll
        for (int m = 0; m < 4; ++m)
#pragma unroll
            for (int n = 0; n < 4; ++n) acc[m][n] = MFMA16(a[m], b[n], acc[m][n]);
        __syncthreads();
    }

#pragma unroll
    for (int m = 0; m < 4; ++m) {
        const long grow0 = rowbase + wr * 64 + m * 16 + g * 4;
#pragma unroll
        for (int n = 0; n < 4; ++n) {
            const long gcol = colbase + wc * 64 + n * 16 + c;
            const float bs = bias[gcol];
#pragma unroll
            for (int r = 0; r < 4; ++r)
                Cout[(grow0 + r) * N + gcol] = acc[m][n][r] + bs;
        }
    }
}

// ---------------------------------------------------------------------------
// RMSNorm + RoPE + transpose to head-major [nh][S][HD]; one wave per (s,h)
// ---------------------------------------------------------------------------
__global__ __launch_bounds__(256) void norm_rope(const unsigned short* __restrict__ proj,
                                                 int nh,
                                                 const float* __restrict__ w,
                                                 const float* __restrict__ cosT,
                                                 const float* __restrict__ sinT,
                                                 unsigned short* __restrict__ outt,
                                                 float oscale) {
    int wv = (blockIdx.x * 256 + threadIdx.x) >> 6;  // over S*nh
    int lane = threadIdx.x & 63;
    int s = wv / nh, h = wv - s * nh;
    const unsigned short* p = proj + (size_t)s * (nh * HD) + h * HD;
    float x1 = b2f(p[lane]);
    float x2 = b2f(p[lane + 64]);
    float ss = x1 * x1 + x2 * x2;
#pragma unroll
    for (int d = 1; d < 64; d <<= 1) ss += __shfl_xor(ss, d);
    float r = rsqrtf(ss * (1.f / 128.f) + 1e-6f);
    x1 *= r * w[lane];
    x2 *= r * w[lane + 64];
    float cs = cosT[s * 64 + lane], sn = sinT[s * 64 + lane];
    unsigned short o1 = f2b((x1 * cs - x2 * sn) * oscale);
    unsigned short o2 = f2b((x2 * cs + x1 * sn) * oscale);
    unsigned short* q = outt + ((size_t)h * SQ + s) * HD;
    q[lane] = o1;
    q[lane + 64] = o2;
}

// ---------------------------------------------------------------------------
// Causal flash attention v8: flash-decode kv-split for uniform load balance.
// 1280 blocks of 4 waves; block id -> (h = id&15, sr = id>>4, s = 79-sr).
// s -> (qb, seg, nseg): qb<8: 1 seg; <16: 2; <24: 3; else 4  (seg len <= 16
// tiles). Longest segments dispatch first (qb descending). Each block
// computes UNNORMALIZED partial o (bf16 [128 rows][128 d]) + per-row (m,l)
// into scratch slots (slot == block id); fcombine merges.
// Per-block machinery identical to v6 (KVB=64 dbuf, swizzles, P in dead K,
// defer-max, exp2 domain). LDS 64KB -> 2 blocks/CU sustained.
// ---------------------------------------------------------------------------
__global__ __launch_bounds__(256, 2) void fattn(const unsigned short* __restrict__ qt,
                                                const unsigned short* __restrict__ kt,
                                                const unsigned short* __restrict__ vt,
                                                unsigned short* __restrict__ pw0,
                                                unsigned short* __restrict__ pw1,
                                                float2* __restrict__ mlb) {
    __shared__ unsigned short Ks[2][KVB * HD];   // [64 kv][128 d], key=((row>>2)&7)<<4
    __shared__ unsigned short Vs[2][HD * KVB];   // [128 d][64 kv], key=(row&7)<<4
    const int tid = threadIdx.x, wid = tid >> 6, lane = tid & 63;
    const int g = lane >> 4, c = lane & 15;
    const int id = blockIdx.x;
    const int h = id & 15, sr = id >> 4, s = 79 - sr;
    int qb, seg, nseg;
    if (s < 8)       { qb = s;                    nseg = 1; seg = 0; }
    else if (s < 24) { qb = 8 + ((s - 8) >> 1);   nseg = 2; seg = (s - 8) & 1; }
    else if (s < 48) { qb = 16 + (s - 24) / 3;    nseg = 3; seg = (s - 24) % 3; }
    else             { qb = 24 + ((s - 48) >> 2); nseg = 4; seg = (s - 48) & 3; }
    const int T = 2 * qb + 2;
    const int t0 = seg * T / nseg, t1 = (seg + 1) * T / nseg;
    const int hk = h >> 1;
    const int row0 = qb * 128 + wid * 32;
    const unsigned short* qh = qt + (size_t)h * SQ * HD;
    const unsigned short* kh = kt + (size_t)hk * SQ * HD;
    const unsigned short* vh = vt + (size_t)hk * HD * SQ;

    bf16x8 qa[2][4];
#pragma unroll
    for (int ks = 0; ks < 4; ++ks) {
        qa[0][ks] = *(const bf16x8*)(qh + (size_t)(row0 + c) * HD + ks * 32 + g * 8);
        qa[1][ks] = *(const bf16x8*)(qh + (size_t)(row0 + 16 + c) * HD + ks * 32 + g * 8);
    }

    f32x4 o[2][8];
#pragma unroll
    for (int m = 0; m < 2; ++m)
#pragma unroll
        for (int df = 0; df < 8; ++df) o[m][df] = (f32x4){0.f, 0.f, 0.f, 0.f};
    float mrow[2][4], lrow[2][4];
#pragma unroll
    for (int m = 0; m < 2; ++m)
#pragma unroll
        for (int r = 0; r < 4; ++r) { mrow[m][r] = -1e30f; lrow[m][r] = 0.f; }

    auto stage = [&](int b, int t) {
        const int kv0 = t * KVB;
#pragma unroll
        for (int i = 0; i < 4; ++i) {
            const int gi = wid * 4 + i;
            const int P = gi * 1024 + lane * 16;
            const int rk = P >> 8;                                  // K row
            const int Uk = (P & 255) ^ (((rk >> 2) & 7) << 4);
            gload_lds16(kh + (size_t)(kv0 + rk) * HD + (Uk >> 1),
                        (char*)Ks[b] + gi * 1024);
            const int rv = P >> 7;                                  // V row (d)
            const int Uv = (P & 127) ^ ((rv & 7) << 4);
            gload_lds16(vh + (size_t)rv * SQ + kv0 + (Uv >> 1),
                        (char*)Vs[b] + gi * 1024);
        }
    };

    stage(0, t0);
    asm volatile("s_waitcnt vmcnt(0)" ::: "memory");
    __syncthreads();

    int bcur = 0;
    for (int j = t0; j < t1; ++j) {
        const int kv0 = j * KVB;
        if (j + 1 < t1) stage(bcur ^ 1, j + 1);

        const bool act = (kv0 <= row0 + 31);   // wave-uniform
        f32x4 sa[2][4];
#pragma unroll
        for (int m = 0; m < 2; ++m)
#pragma unroll
            for (int nf = 0; nf < 4; ++nf) sa[m][nf] = (f32x4){0.f, 0.f, 0.f, 0.f};
        if (act) {
            __builtin_amdgcn_s_setprio(1);
#pragma unroll
            for (int nf = 0; nf < 4; ++nf) {
                const int krow = (c << 2) + nf;
                const int key = (c & 7) << 4;  // == ((krow>>2)&7)<<4
#pragma unroll
                for (int ks = 0; ks < 4; ++ks) {
                    bf16x8 kf = *(const bf16x8*)((const char*)Ks[bcur] + krow * 256 +
                                                 ((ks * 64 + g * 16) ^ key));
                    sa[0][nf] = MFMA16(qa[0][ks], kf, sa[0][nf]);
                    sa[1][nf] = MFMA16(qa[1][ks], kf, sa[1][nf]);
                }
            }
            __builtin_amdgcn_s_setprio(0);
        }
        // ---- retire K[bcur]: all waves' K reads done -> reuse as P buffer.
        asm volatile("s_waitcnt lgkmcnt(0)" ::: "memory");
        __builtin_amdgcn_s_barrier();
        char* plw = (char*)Ks[bcur] + wid * 4096;   // 32 rows x 128B per wave

        if (act) {
            // ---- causal mask (col = kv0 + 4c + nf); only near the diagonal
            if (kv0 + 63 > row0) {
#pragma unroll
                for (int m = 0; m < 2; ++m) {
                    const int rb = row0 + m * 16;
#pragma unroll
                    for (int nf = 0; nf < 4; ++nf) {
                        const int col = kv0 + (c << 2) + nf;
#pragma unroll
                        for (int r = 0; r < 4; ++r) {
                            int row = rb + g * 4 + r;
                            if (col > row) sa[m][nf][r] = -1e30f;
                        }
                    }
                }
            }
            // ---- online softmax in exp2 domain, defer-max (T13)
            float nmax[2][4];
            int small = 1;
#pragma unroll
            for (int m = 0; m < 2; ++m)
#pragma unroll
                for (int r = 0; r < 4; ++r) {
                    float mx = fmaxf(fmaxf(sa[m][0][r], sa[m][1][r]),
                                     fmaxf(sa[m][2][r], sa[m][3][r]));
                    mx = rowmax16(mx);
                    nmax[m][r] = mx;
                    small &= (mx <= mrow[m][r] + 8.0f);
                }
            if (!__all(small)) {
#pragma unroll
                for (int m = 0; m < 2; ++m) {
                    float psc[4];
#pragma unroll
                    for (int r = 0; r < 4; ++r) {
                        float mn = fmaxf(mrow[m][r], nmax[m][r]);
                        psc[r] = __builtin_amdgcn_exp2f(mrow[m][r] - mn);
                        mrow[m][r] = mn;
                        lrow[m][r] *= psc[r];
                    }
#pragma unroll
                    for (int df = 0; df < 8; ++df)
#pragma unroll
                        for (int r = 0; r < 4; ++r) o[m][df][r] *= psc[r];
                }
            }
#pragma unroll
            for (int m = 0; m < 2; ++m)
#pragma unroll
                for (int r = 0; r < 4; ++r) {
                    float rs = 0.f;
#pragma unroll
                    for (int nf = 0; nf < 4; ++nf) {
                        float p = __builtin_amdgcn_exp2f(sa[m][nf][r] - mrow[m][r]);
                        sa[m][nf][r] = p;
                        rs += p;
                    }
                    lrow[m][r] += rowsum16(rs);
                }
            // ---- P -> LDS (cvt_pk + b64, swizzled), into dead K region
#pragma unroll
            for (int m = 0; m < 2; ++m)
#pragma unroll
                for (int r = 0; r < 4; ++r) {
                    unsigned int lo, hi;
                    asm("v_cvt_pk_bf16_f32 %0, %1, %2"
                        : "=v"(lo) : "v"(sa[m][0][r]), "v"(sa[m][1][r]));
                    asm("v_cvt_pk_bf16_f32 %0, %1, %2"
                        : "=v"(hi) : "v"(sa[m][2][r]), "v"(sa[m][3][r]));
                    const int row = m * 16 + g * 4 + r;
                    const int pcol = (c * 8) ^ ((row & 7) << 4);
                    *(uint2*)(plw + row * 128 + pcol) = make_uint2(lo, hi);
                }
            asm volatile("s_waitcnt lgkmcnt(0)" ::: "memory");
            // ---- PV
            __builtin_amdgcn_s_setprio(1);
#pragma unroll
            for (int ks = 0; ks < 2; ++ks) {
                const int pk_ = (ks * 64 + g * 16) ^ ((c & 7) << 4);
                bf16x8 pa0 = *(const bf16x8*)(plw + c * 128 + pk_);
                bf16x8 pa1 = *(const bf16x8*)(plw + (16 + c) * 128 + pk_);
#pragma unroll
                for (int df = 0; df < 8; ++df) {
                    const int rd = df * 16 + c;
                    bf16x8 vb = *(const bf16x8*)((const char*)Vs[bcur] + rd * 128 +
                                                 ((ks * 64 + g * 16) ^ ((rd & 7) << 4)));
                    o[0][df] = MFMA16(pa0, vb, o[0][df]);
                    o[1][df] = MFMA16(pa1, vb, o[1][df]);
                }
            }
            __builtin_amdgcn_s_setprio(0);
        }

        asm volatile("s_waitcnt vmcnt(0)" ::: "memory");
        __syncthreads();
        bcur ^= 1;
    }

    // ---- write UNNORMALIZED partials: o bf16 [128][128] + (m,l) per row
    unsigned short* op = (id < 1024) ? (pw0 + (size_t)id * 16384)
                                     : (pw1 + (size_t)(id - 1024) * 16384);
#pragma unroll
    for (int m = 0; m < 2; ++m)
#pragma unroll
        for (int df = 0; df < 8; ++df)
#pragma unroll
            for (int r = 0; r < 4; ++r) {
                const int row = wid * 32 + m * 16 + g * 4 + r;
                op[row * 128 + df * 16 + c] = f2b(o[m][df][r]);
            }
    if (c == 0) {
#pragma unroll
        for (int m = 0; m < 2; ++m)
#pragma unroll
            for (int r = 0; r < 4; ++r) {
                const int row = wid * 32 + m * 16 + g * 4 + r;
                mlb[(size_t)id * 128 + row] = make_float2(mrow[m][r], lrow[m][r]);
            }
    }
}

// ---------------------------------------------------------------------------
// Combine kv-split partials: out[row, h*HD + d] = sum_k w_k o_k / sum_k w_k l_k
// with w_k = exp2(m_k - M). 8 rows per 256-thread block (32 lanes x 4 d each).
// ---------------------------------------------------------------------------
__global__ __launch_bounds__(256) void fcombine(const unsigned short* __restrict__ pw0,
                                                const unsigned short* __restrict__ pw1,
                                                const float2* __restrict__ mlb,
                                                unsigned short* __restrict__ aout) {
    const int gid = blockIdx.x * 8 + (threadIdx.x >> 5);  // (h, row) job
    const int h = gid >> 12, row = gid & 4095;
    const int qb = row >> 7, rloc = row & 127;
    const int d0 = (threadIdx.x & 31) * 4;
    int nseg, sbase;
    if (qb < 8)       { nseg = 1; sbase = qb; }
    else if (qb < 16) { nseg = 2; sbase = 8 + 2 * (qb - 8); }
    else if (qb < 24) { nseg = 3; sbase = 24 + 3 * (qb - 16); }
    else              { nseg = 4; sbase = 48 + 4 * (qb - 24); }
    float M = -1e30f;
    for (int k = 0; k < nseg; ++k) {
        const int slot = (79 - (sbase + k)) * 16 + h;
        M = fmaxf(M, mlb[(size_t)slot * 128 + rloc].x);
    }
    float L = 0.f, a0 = 0.f, a1 = 0.f, a2 = 0.f, a3 = 0.f;
    for (int k = 0; k < nseg; ++k) {
        const int slot = (79 - (sbase + k)) * 16 + h;
        const float2 ml = mlb[(size_t)slot * 128 + rloc];
        const float wgt = exp2f(ml.x - M);
        L += wgt * ml.y;
        const unsigned short* op = (slot < 1024) ? (pw0 + (size_t)slot * 16384)
                                                 : (pw1 + (size_t)(slot - 1024) * 16384);
        const ushort4 ov = *(const ushort4*)(op + rloc * 128 + d0);
        a0 += wgt * b2f(ov.x);
        a1 += wgt * b2f(ov.y);
        a2 += wgt * b2f(ov.z);
        a3 += wgt * b2f(ov.w);
    }
    const float inv = 1.f / L;
    ushort4 r4;
    r4.x = f2b(a0 * inv); r4.y = f2b(a1 * inv);
    r4.z = f2b(a2 * inv); r4.w = f2b(a3 * inv);
    *(ushort4*)(aout + (size_t)row * QD + h * HD + d0) = r4;
}

// ---------------------------------------------------------------------------
extern "C" void kernel_launch(void* const* d_in, const int* in_sizes, int n_in,
                              void* d_out, int out_size, void* d_ws, size_t ws_size,
                              hipStream_t stream) {
    const int*   positions = (const int*)d_in[0];
    const float* hidden    = (const float*)d_in[1];
    const float* wq        = (const float*)d_in[2];
    const float* bq        = (const float*)d_in[3];
    const float* wk        = (const float*)d_in[4];
    const float* bk        = (const float*)d_in[5];
    const float* wv        = (const float*)d_in[6];
    const float* bv        = (const float*)d_in[7];
    const float* wo        = (const float*)d_in[8];
    const float* bo        = (const float*)d_in[9];
    const float* qnw       = (const float*)d_in[10];
    const float* knw       = (const float*)d_in[11];
    float* out = (float*)d_out;

    char* w = (char*)d_ws;
    unsigned short* hidden_b = (unsigned short*)(w);                 // 16 MB
    unsigned short* wqkv_b   = (unsigned short*)(w + 16777216);      // 16 MB (wq|wk|wv)
    unsigned short* wq_b     = (unsigned short*)(w + 16777216);
    unsigned short* wk_b     = (unsigned short*)(w + 25165824);
    unsigned short* wv_b     = (unsigned short*)(w + 29360128);
    unsigned short* wo_b     = (unsigned short*)(w + 33554432);      //  8 MB (LIVE to end)
    unsigned short* qproj    = (unsigned short*)(w + 41943040);      // 16 MB (-> attn out)
    unsigned short* kproj    = (unsigned short*)(w + 58720256);      //  8 MB
    unsigned short* q_t      = (unsigned short*)(w + 67108864);      // 16 MB
    unsigned short* k_t      = (unsigned short*)(w + 83886080);      //  8 MB
    unsigned short* v_t      = (unsigned short*)(w + 92274688);      //  8 MB
    float*          cosT     = (float*)(w + 100663296);              //  1 MB
    float*          sinT     = (float*)(w + 101711872);              //  1 MB
    unsigned short* attn     = qproj;   // qproj consumed by norm_rope before fattn
    // fattn partial scratch (regions dead by the time fattn runs):
    unsigned short* pw0      = (unsigned short*)(w);                 // 32 MB: slots 0..1023
    unsigned short* pw1      = (unsigned short*)(w + 58720256);      //  8 MB: slots 1024..1279
    float2*         mlb      = (float2*)(w + 100663296);             // 1.3 MB (cos/sin dead)

    cvt_all<<<20480, 256, 0, stream>>>(hidden, wq, wk, wv, wo,
                                       hidden_b, wq_b, wk_b, wv_b, wo_b);
    rope_table<<<SQ * 64 / 256, 256, 0, stream>>>(positions, cosT, sinT);
    gemm_qkv<<<dim3(32, 32), 256, 0, stream>>>(hidden_b, wqkv_b, bq, bk, bv,
                                               qproj, kproj, v_t);
    norm_rope<<<SQ * NH / 4, 256, 0, stream>>>(qproj, NH, qnw, cosT, sinT, q_t,
                                               (float)(0.08838834764831845 * 1.4426950408889634));
    norm_rope<<<SQ * NKV / 4, 256, 0, stream>>>(kproj, NKV, knw, cosT, sinT, k_t, 1.0f);
    fattn<<<1280, 256, 0, stream>>>(q_t, k_t, v_t, pw0, pw1, mlb);
    fcombine<<<8192, 256, 0, stream>>>(pw0, pw1, mlb, attn);
    gemm_o<<<dim3(QD / 128, SQ / 128), 256, 0, stream>>>(attn, wo_b, bo, out, SQ, QD, HIDN);
}